// Round 6
// baseline (2522.703 us; speedup 1.0000x reference)
//
#include <hip/hip_runtime.h>
#include <hip/hip_bf16.h>

#define B_ 2
#define S_ 2048
#define D_ 1024
#define H_ 16
#define DH_ 64
#define FF_ 4096
#define MTOK 4096  // B_*S_

using bf16 = __hip_bfloat16;
typedef short s16x8 __attribute__((ext_vector_type(8)));
typedef float f32x4 __attribute__((ext_vector_type(4)));

#define MFMA_BF16(A, Bv, C) __builtin_amdgcn_mfma_f32_16x16x32_bf16(A, Bv, C, 0, 0, 0)

__device__ __forceinline__ void load_lds16(const void* g, void* l) {
  __builtin_amdgcn_global_load_lds(
      (const __attribute__((address_space(1))) void*)g,
      (__attribute__((address_space(3))) void*)l, 16, 0, 0);
}

__device__ __forceinline__ float bfr2f(unsigned short u) {
  return __uint_as_float(((unsigned)u) << 16);
}
__device__ __forceinline__ unsigned short f2bfr(float f) {
  __hip_bfloat16 h = __float2bfloat16(f);
  return *(unsigned short*)&h;
}

// ---------------------------------------------------------------------------
// f32 -> bf16 conversion (inputs are float32 per reference; established
// empirically: direct-bf16 reads NaN'd, converted reads give sane values).
// Sniffer retained as cheap insurance against a bf16-input variant.
// ---------------------------------------------------------------------------
__device__ int sniff_is_bf16(const unsigned* Xw) {
  int cnt = 0;
  for (int i = 0; i < 64; i++) {
    unsigned w = Xw[i];
    unsigned short h0 = (unsigned short)(w & 0xFFFF);
    unsigned short h1 = (unsigned short)(w >> 16);
    int e0 = (h0 >> 7) & 0xFF, e1 = (h1 >> 7) & 0xFF;
    if ((e0 >= 100 && e0 <= 140) || (h0 & 0x7FFF) == 0) cnt++;
    if ((e1 >= 100 && e1 <= 140) || (h1 & 0x7FFF) == 0) cnt++;
  }
  return cnt >= 110;
}

__global__ __launch_bounds__(256) void convert_kernel(
    const void* __restrict__ src, const unsigned* __restrict__ Xs,
    bf16* __restrict__ dst, int n) {
  __shared__ int isbf;
  if (threadIdx.x == 0) isbf = sniff_is_bf16(Xs);
  __syncthreads();
  int i = (blockIdx.x * 256 + threadIdx.x) * 4;
  if (i >= n) return;
  ushort4 o;
  if (isbf) {
    o = *(const ushort4*)((const unsigned short*)src + i);
  } else {
    const float4 f = *(const float4*)((const float*)src + i);
    o.x = f2bfr(f.x); o.y = f2bfr(f.y); o.z = f2bfr(f.z); o.w = f2bfr(f.w);
  }
  *(ushort4*)((unsigned short*)dst + i) = o;
}

// ---------------------------------------------------------------------------
// B^T-form MFMA GEMM: out[m][n] = sum_k A[m][k] * Bw[n][k]  (+ epilogue)
// modes: 0 = store Q/K head-major [B,H,S,DH]
//        1 = store V transposed   [B,H,DH,S]
//        2 = out = acc + res                  (att_out + X)
//        3 = out = relu(acc + bias)           (FFN1)
//        4 = out = acc + bias + res           (FFN2 + residual)
// ---------------------------------------------------------------------------
__global__ __launch_bounds__(256) void gemm_bt(
    const bf16* __restrict__ A, const bf16* __restrict__ Bw,
    bf16* __restrict__ out, const bf16* __restrict__ bias,
    const bf16* __restrict__ res, int M, int N, int K, int mode) {
  __shared__ alignas(16) bf16 As[128 * 32];
  __shared__ alignas(16) bf16 Bs[128 * 32];
  const int tid = threadIdx.x;
  const int wave = tid >> 6;
  const int lane = tid & 63;
  const int col = lane & 15;
  const int quad = lane >> 4;
  const int m0 = blockIdx.y * 128;
  const int n0 = blockIdx.x * 128;
  const int wm = (wave >> 1) * 64;
  const int wn = (wave & 1) * 64;

  const int srow = wave * 32 + (lane >> 2);
  const int skoff = (lane & 3) * 8;
  const bf16* ag = A + (size_t)(m0 + srow) * K + skoff;
  const bf16* bg = Bw + (size_t)(n0 + srow) * K + skoff;
  bf16* asl = As + wave * 1024;
  bf16* bsl = Bs + wave * 1024;

  const f32x4 fz = {0.f, 0.f, 0.f, 0.f};
  f32x4 acc[4][4];
  for (int i = 0; i < 4; i++)
    for (int j = 0; j < 4; j++) acc[i][j] = fz;

  for (int k0 = 0; k0 < K; k0 += 32) {
    load_lds16(ag + k0, asl);
    load_lds16(ag + k0 + (size_t)16 * K, asl + 512);
    load_lds16(bg + k0, bsl);
    load_lds16(bg + k0 + (size_t)16 * K, bsl + 512);
    __syncthreads();
    s16x8 Af[4], Bf[4];
    for (int t = 0; t < 4; t++) {
      Af[t] = *(const s16x8*)(As + (wm + t * 16 + col) * 32 + quad * 8);
      Bf[t] = *(const s16x8*)(Bs + (wn + t * 16 + col) * 32 + quad * 8);
    }
    for (int mt = 0; mt < 4; mt++)
      for (int nt = 0; nt < 4; nt++)
        acc[mt][nt] = MFMA_BF16(Af[mt], Bf[nt], acc[mt][nt]);
    __syncthreads();
  }

  // epilogue: C/D layout col=lane&15 (n), row=quad*4+r (m)
  for (int mt = 0; mt < 4; mt++) {
    for (int nt = 0; nt < 4; nt++) {
      for (int r = 0; r < 4; r++) {
        int gm = m0 + wm + mt * 16 + quad * 4 + r;
        int gn = n0 + wn + nt * 16 + col;
        float v = acc[mt][nt][r];
        if (mode == 0) {
          int b = gm >> 11, s = gm & 2047, h = gn >> 6, dh = gn & 63;
          out[(((size_t)(b * H_ + h) * S_ + s) << 6) + dh] = __float2bfloat16(v);
        } else if (mode == 1) {
          int b = gm >> 11, s = gm & 2047, h = gn >> 6, dh = gn & 63;
          out[(((size_t)(b * H_ + h) * DH_ + dh) << 11) + s] = __float2bfloat16(v);
        } else {
          size_t idx = (size_t)gm * N + gn;
          if (mode == 2) {
            v += __bfloat162float(res[idx]);
          } else if (mode == 3) {
            v += __bfloat162float(bias[gn]);
            v = fmaxf(v, 0.f);
          } else {
            v += __bfloat162float(bias[gn]) + __bfloat162float(res[idx]);
          }
          out[idx] = __float2bfloat16(v);
        }
      }
    }
  }
}

// ---------------------------------------------------------------------------
// Flash-style attention, one wave per (b,h, 16 q-rows). relu-mask -> single
// pass exp(max(s,0)); l >= S so no div hazard.
// Q,K: [B,H,S,64]; Vt: [B,H,64,S]; ctx out: [B*S, D] token-major.
// ---------------------------------------------------------------------------
__global__ __launch_bounds__(64) void attn_kernel(
    const bf16* __restrict__ Q, const bf16* __restrict__ Kb,
    const bf16* __restrict__ Vt, bf16* __restrict__ ctx) {
  const int lane = threadIdx.x;
  const int col = lane & 15, quad = lane >> 4;
  const int bh = blockIdx.y;
  const int q0 = blockIdx.x * 16;
  const bf16* Qp = Q + (size_t)bh * S_ * DH_;
  const bf16* Kp = Kb + (size_t)bh * S_ * DH_;
  const bf16* Vp = Vt + (size_t)bh * DH_ * S_;
  __shared__ alignas(16) bf16 P[16 * 32];

  s16x8 qf0 = *(const s16x8*)(Qp + (size_t)(q0 + col) * DH_ + quad * 8);
  s16x8 qf1 = *(const s16x8*)(Qp + (size_t)(q0 + col) * DH_ + 32 + quad * 8);
  const f32x4 fz = {0.f, 0.f, 0.f, 0.f};
  f32x4 accv[4];
  for (int t = 0; t < 4; t++) accv[t] = fz;
  float lpart[4] = {0.f, 0.f, 0.f, 0.f};

  for (int kt = 0; kt < S_; kt += 32) {
    const bf16* kp0 = Kp + (size_t)(kt + col) * DH_;
    const bf16* kp1 = Kp + (size_t)(kt + 16 + col) * DH_;
    s16x8 kf00 = *(const s16x8*)(kp0 + quad * 8);
    s16x8 kf01 = *(const s16x8*)(kp0 + 32 + quad * 8);
    s16x8 kf10 = *(const s16x8*)(kp1 + quad * 8);
    s16x8 kf11 = *(const s16x8*)(kp1 + 32 + quad * 8);
    f32x4 s0 = fz, s1 = fz;
    s0 = MFMA_BF16(qf0, kf00, s0);
    s0 = MFMA_BF16(qf1, kf01, s0);
    s1 = MFMA_BF16(qf0, kf10, s1);
    s1 = MFMA_BF16(qf1, kf11, s1);
    for (int r = 0; r < 4; r++) {
      float e0 = __expf(fmaxf(s0[r] * 0.125f, 0.f));
      float e1 = __expf(fmaxf(s1[r] * 0.125f, 0.f));
      lpart[r] += e0 + e1;
      P[(quad * 4 + r) * 32 + col] = __float2bfloat16(e0);
      P[(quad * 4 + r) * 32 + col + 16] = __float2bfloat16(e1);
    }
    __syncthreads();
    s16x8 pf = *(const s16x8*)(P + col * 32 + quad * 8);
    for (int t = 0; t < 4; t++) {
      s16x8 vf = *(const s16x8*)(Vp + (size_t)(t * 16 + col) * S_ + kt + quad * 8);
      accv[t] = MFMA_BF16(pf, vf, accv[t]);
    }
    __syncthreads();
  }
  for (int off = 1; off < 16; off <<= 1)
    for (int r = 0; r < 4; r++) lpart[r] += __shfl_xor(lpart[r], off, 64);
  const int b = bh >> 4, h = bh & 15;
  for (int r = 0; r < 4; r++) {
    float rl = 1.f / lpart[r];
    size_t base = (size_t)(b * S_ + q0 + quad * 4 + r) * D_ + h * DH_;
    for (int t = 0; t < 4; t++)
      ctx[base + t * 16 + col] = __float2bfloat16(accv[t][r] * rl);
  }
}

// ---------------------------------------------------------------------------
// LayerNorm over last dim (1024), one block of 256 per row.
// bf16 in; bf16 out (intermediate) or f32 out (final — d_out is float32!).
// ---------------------------------------------------------------------------
__device__ __forceinline__ void ln_row(
    const bf16* __restrict__ x, const bf16* __restrict__ g,
    const bf16* __restrict__ b, int row, int tid, float vout[4]) {
  const int lane = tid & 63, wave = tid >> 6;
  const unsigned short* xr = (const unsigned short*)x + (size_t)row * D_;
  ushort4 xv = *(const ushort4*)(xr + tid * 4);
  float v[4];
  v[0] = bfr2f(xv.x); v[1] = bfr2f(xv.y); v[2] = bfr2f(xv.z); v[3] = bfr2f(xv.w);
  float sum = v[0] + v[1] + v[2] + v[3];
  float sq = v[0] * v[0] + v[1] * v[1] + v[2] * v[2] + v[3] * v[3];
  for (int off = 32; off > 0; off >>= 1) {
    sum += __shfl_xor(sum, off, 64);
    sq += __shfl_xor(sq, off, 64);
  }
  __shared__ float red[4][2];
  if (lane == 0) { red[wave][0] = sum; red[wave][1] = sq; }
  __syncthreads();
  sum = red[0][0] + red[1][0] + red[2][0] + red[3][0];
  sq = red[0][1] + red[1][1] + red[2][1] + red[3][1];
  float mu = sum * (1.f / D_);
  float var = sq * (1.f / D_) - mu * mu;
  float rs = rsqrtf(var + 1e-5f);
  ushort4 gv = *(const ushort4*)((const unsigned short*)g + tid * 4);
  ushort4 bv = *(const ushort4*)((const unsigned short*)b + tid * 4);
  vout[0] = (v[0] - mu) * rs * bfr2f(gv.x) + bfr2f(bv.x);
  vout[1] = (v[1] - mu) * rs * bfr2f(gv.y) + bfr2f(bv.y);
  vout[2] = (v[2] - mu) * rs * bfr2f(gv.z) + bfr2f(bv.z);
  vout[3] = (v[3] - mu) * rs * bfr2f(gv.w) + bfr2f(bv.w);
}

__global__ __launch_bounds__(256) void ln_kernel_bf16(
    const bf16* __restrict__ x, const bf16* __restrict__ g,
    const bf16* __restrict__ b, bf16* __restrict__ out) {
  const int row = blockIdx.x, tid = threadIdx.x;
  float v[4];
  ln_row(x, g, b, row, tid, v);
  ushort4 o;
  o.x = f2bfr(v[0]); o.y = f2bfr(v[1]); o.z = f2bfr(v[2]); o.w = f2bfr(v[3]);
  *(ushort4*)((unsigned short*)out + (size_t)row * D_ + tid * 4) = o;
}

__global__ __launch_bounds__(256) void ln_kernel_f32(
    const bf16* __restrict__ x, const bf16* __restrict__ g,
    const bf16* __restrict__ b, float* __restrict__ out) {
  const int row = blockIdx.x, tid = threadIdx.x;
  float v[4];
  ln_row(x, g, b, row, tid, v);
  float4 o = {v[0], v[1], v[2], v[3]};
  *(float4*)(out + (size_t)row * D_ + tid * 4) = o;
}

// ---------------------------------------------------------------------------
// Workspace: 46.4 MB peak via lifetime-aliased 8 MB slots.
//   slotA  0- 8: Qb   -> z1 (post-attn)  -> W1c (post-LN1)
//   slotB  8-16: Kbf  -> y  (post-attn)
//   slotC 16-24: Vt   -> W2c (post-attn)
//   slotD 24-32: ctx  -> hh chunk (post-outproj)
//   slotE 32-40: Xc   -> z2 (post-outproj)
//   40-46: Wqc, Wkc, Woc;  46-46.4: ln/bias vectors
// ---------------------------------------------------------------------------
extern "C" void kernel_launch(void* const* d_in, const int* in_sizes, int n_in,
                              void* d_out, int out_size, void* d_ws, size_t ws_size,
                              hipStream_t stream) {
  (void)in_sizes; (void)n_in; (void)out_size; (void)ws_size;
  const unsigned* Xs = (const unsigned*)d_in[0];

  char* ws = (char*)d_ws;
  const size_t MB = 1024 * 1024;
  bf16* slotA = (bf16*)(ws + 0 * MB);
  bf16* slotB = (bf16*)(ws + 8 * MB);
  bf16* slotC = (bf16*)(ws + 16 * MB);
  bf16* slotD = (bf16*)(ws + 24 * MB);
  bf16* slotE = (bf16*)(ws + 32 * MB);
  bf16* Wqc   = (bf16*)(ws + 40 * MB);
  bf16* Wkc   = (bf16*)(ws + 42 * MB);
  bf16* Woc   = (bf16*)(ws + 44 * MB);
  bf16* ln1g  = (bf16*)(ws + 46 * MB + 0 * 65536);
  bf16* ln1b  = (bf16*)(ws + 46 * MB + 1 * 65536);
  bf16* ln2g  = (bf16*)(ws + 46 * MB + 2 * 65536);
  bf16* ln2b  = (bf16*)(ws + 46 * MB + 3 * 65536);
  bf16* b1c   = (bf16*)(ws + 46 * MB + 4 * 65536);
  bf16* b2c   = (bf16*)(ws + 46 * MB + 5 * 65536);

  bf16* Qb  = slotA;
  bf16* Kbf = slotB;
  bf16* Vt  = slotC;
  bf16* ctx = slotD;
  bf16* Xc  = slotE;
  bf16* z1  = slotA;
  bf16* y   = slotB;
  bf16* W1c = slotA;
  bf16* W2c = slotC;
  bf16* hhc = slotD;
  bf16* z2  = slotE;

  dim3 blk(256);
  auto conv = [&](const void* src, bf16* dst, int n) {
    convert_kernel<<<dim3((n / 4 + 255) / 256), blk, 0, stream>>>(src, Xs, dst, n);
  };

  // Phase 0: convert X, attention weights, vectors.
  conv(d_in[0], Xc, MTOK * D_);
  conv(d_in[1], Wqc, D_ * D_);
  conv(d_in[2], Wkc, D_ * D_);
  conv(d_in[3], Woc, D_ * D_);
  conv(d_in[4], ln1g, D_);
  conv(d_in[5], ln1b, D_);
  conv(d_in[6], ln2g, D_);
  conv(d_in[7], ln2b, D_);
  conv(d_in[9], b1c, FF_);
  conv(d_in[11], b2c, D_);

  // Phase 1: QKV + attention + out-proj + LN1.
  gemm_bt<<<dim3(8, 32), blk, 0, stream>>>(Xc, Wqc, Qb, nullptr, nullptr, MTOK, D_, D_, 0);
  gemm_bt<<<dim3(8, 32), blk, 0, stream>>>(Xc, Wkc, Kbf, nullptr, nullptr, MTOK, D_, D_, 0);
  gemm_bt<<<dim3(8, 32), blk, 0, stream>>>(Xc, Woc, Vt, nullptr, nullptr, MTOK, D_, D_, 1);
  attn_kernel<<<dim3(S_ / 16, B_ * H_), dim3(64), 0, stream>>>(Qb, Kbf, Vt, ctx);
  gemm_bt<<<dim3(8, 32), blk, 0, stream>>>(ctx, Woc, z1, nullptr, Xc, MTOK, D_, D_, 2);
  ln_kernel_bf16<<<dim3(MTOK), blk, 0, stream>>>(z1, ln1g, ln1b, y);

  // Phase 2: FFN weights into freed slots, chunked FFN, final LN -> f32 out.
  conv(d_in[8], W1c, FF_ * D_);
  conv(d_in[10], W2c, D_ * FF_);
  for (int c = 0; c < 4; c++) {
    const bf16* yc = y + (size_t)c * 1024 * D_;
    bf16* z2c = z2 + (size_t)c * 1024 * D_;
    gemm_bt<<<dim3(32, 8), blk, 0, stream>>>(yc, W1c, hhc, b1c, nullptr, 1024, FF_, D_, 3);
    gemm_bt<<<dim3(8, 8), blk, 0, stream>>>(hhc, W2c, z2c, b2c, yc, 1024, D_, FF_, 4);
  }
  ln_kernel_f32<<<dim3(MTOK), blk, 0, stream>>>(z2, ln2g, ln2b, (float*)d_out);
}

// Round 7
// 1458.490 us; speedup vs baseline: 1.7297x; 1.7297x over previous
//
#include <hip/hip_runtime.h>
#include <hip/hip_bf16.h>

#define B_ 2
#define S_ 2048
#define D_ 1024
#define H_ 16
#define DH_ 64
#define FF_ 4096
#define MTOK 4096  // B_*S_

using bf16 = __hip_bfloat16;
typedef short s16x8 __attribute__((ext_vector_type(8)));
typedef float f32x4 __attribute__((ext_vector_type(4)));

#define MFMA_BF16(A, Bv, C) __builtin_amdgcn_mfma_f32_16x16x32_bf16(A, Bv, C, 0, 0, 0)

__device__ __forceinline__ void load_lds16(const void* g, void* l) {
  __builtin_amdgcn_global_load_lds(
      (const __attribute__((address_space(1))) void*)g,
      (__attribute__((address_space(3))) void*)l, 16, 0, 0);
}

__device__ __forceinline__ float bfr2f(unsigned short u) {
  return __uint_as_float(((unsigned)u) << 16);
}
__device__ __forceinline__ unsigned short f2bfr(float f) {
  __hip_bfloat16 h = __float2bfloat16(f);
  return *(unsigned short*)&h;
}

// ---------------------------------------------------------------------------
// Inputs are float32 (established r5->r6); sniffer kept as insurance.
// ---------------------------------------------------------------------------
__device__ int sniff_is_bf16(const unsigned* Xw) {
  int cnt = 0;
  for (int i = 0; i < 64; i++) {
    unsigned w = Xw[i];
    unsigned short h0 = (unsigned short)(w & 0xFFFF);
    unsigned short h1 = (unsigned short)(w >> 16);
    int e0 = (h0 >> 7) & 0xFF, e1 = (h1 >> 7) & 0xFF;
    if ((e0 >= 100 && e0 <= 140) || (h0 & 0x7FFF) == 0) cnt++;
    if ((e1 >= 100 && e1 <= 140) || (h1 & 0x7FFF) == 0) cnt++;
  }
  return cnt >= 110;
}

__global__ __launch_bounds__(256) void convert_kernel(
    const void* __restrict__ src, const unsigned* __restrict__ Xs,
    bf16* __restrict__ dst, int n) {
  __shared__ int isbf;
  if (threadIdx.x == 0) isbf = sniff_is_bf16(Xs);
  __syncthreads();
  int i = (blockIdx.x * 256 + threadIdx.x) * 4;
  if (i >= n) return;
  ushort4 o;
  if (isbf) {
    o = *(const ushort4*)((const unsigned short*)src + i);
  } else {
    const float4 f = *(const float4*)((const float*)src + i);
    o.x = f2bfr(f.x); o.y = f2bfr(f.y); o.z = f2bfr(f.z); o.w = f2bfr(f.w);
  }
  *(ushort4*)((unsigned short*)dst + i) = o;
}

// ---------------------------------------------------------------------------
// B^T-form MFMA GEMM: out[m][n] = sum_k A[m][k] * Bw[n][k]  (+ epilogue)
// modes: 2 = out = acc + res                  (att_out + X)
//        3 = out = relu(acc + bias)           (FFN1)
//        4 = out = acc + bias + res           (FFN2 + residual)
//        5 = fused QKV: N=3072; gn>>6 selects head 0-47:
//            <16 -> Q head-major [B,H,S,DH] (out)
//            <32 -> K head-major          (aux1)
//            else-> V transposed [B,H,DH,S] (aux2)
// ---------------------------------------------------------------------------
__global__ __launch_bounds__(256) void gemm_bt(
    const bf16* __restrict__ A, const bf16* __restrict__ Bw,
    bf16* __restrict__ out, const bf16* __restrict__ bias,
    const bf16* __restrict__ res, bf16* __restrict__ aux1,
    bf16* __restrict__ aux2, int M, int N, int K, int mode) {
  __shared__ alignas(16) bf16 As[128 * 32];
  __shared__ alignas(16) bf16 Bs[128 * 32];
  const int tid = threadIdx.x;
  const int wave = tid >> 6;
  const int lane = tid & 63;
  const int col = lane & 15;
  const int quad = lane >> 4;
  const int m0 = blockIdx.y * 128;
  const int n0 = blockIdx.x * 128;
  const int wm = (wave >> 1) * 64;
  const int wn = (wave & 1) * 64;

  const int srow = wave * 32 + (lane >> 2);
  const int skoff = (lane & 3) * 8;
  const bf16* ag = A + (size_t)(m0 + srow) * K + skoff;
  const bf16* bg = Bw + (size_t)(n0 + srow) * K + skoff;
  bf16* asl = As + wave * 1024;
  bf16* bsl = Bs + wave * 1024;

  const f32x4 fz = {0.f, 0.f, 0.f, 0.f};
  f32x4 acc[4][4];
  for (int i = 0; i < 4; i++)
    for (int j = 0; j < 4; j++) acc[i][j] = fz;

  for (int k0 = 0; k0 < K; k0 += 32) {
    load_lds16(ag + k0, asl);
    load_lds16(ag + k0 + (size_t)16 * K, asl + 512);
    load_lds16(bg + k0, bsl);
    load_lds16(bg + k0 + (size_t)16 * K, bsl + 512);
    __syncthreads();
    s16x8 Af[4], Bf[4];
    for (int t = 0; t < 4; t++) {
      Af[t] = *(const s16x8*)(As + (wm + t * 16 + col) * 32 + quad * 8);
      Bf[t] = *(const s16x8*)(Bs + (wn + t * 16 + col) * 32 + quad * 8);
    }
    for (int mt = 0; mt < 4; mt++)
      for (int nt = 0; nt < 4; nt++)
        acc[mt][nt] = MFMA_BF16(Af[mt], Bf[nt], acc[mt][nt]);
    __syncthreads();
  }

  // epilogue: C/D layout col=lane&15 (n), row=quad*4+r (m)
  for (int mt = 0; mt < 4; mt++) {
    for (int nt = 0; nt < 4; nt++) {
      for (int r = 0; r < 4; r++) {
        int gm = m0 + wm + mt * 16 + quad * 4 + r;
        int gn = n0 + wn + nt * 16 + col;
        float v = acc[mt][nt][r];
        if (mode == 5) {
          int b = gm >> 11, s = gm & 2047, hx = gn >> 6, dh = gn & 63;
          if (hx < 16) {
            out[(((size_t)(b * H_ + hx) * S_ + s) << 6) + dh] = __float2bfloat16(v);
          } else if (hx < 32) {
            aux1[(((size_t)(b * H_ + hx - 16) * S_ + s) << 6) + dh] = __float2bfloat16(v);
          } else {
            aux2[(((size_t)(b * H_ + hx - 32) * DH_ + dh) << 11) + s] = __float2bfloat16(v);
          }
        } else {
          size_t idx = (size_t)gm * N + gn;
          if (mode == 2) {
            v += __bfloat162float(res[idx]);
          } else if (mode == 3) {
            v += __bfloat162float(bias[gn]);
            v = fmaxf(v, 0.f);
          } else {
            v += __bfloat162float(bias[gn]) + __bfloat162float(res[idx]);
          }
          out[idx] = __float2bfloat16(v);
        }
      }
    }
  }
}

// ---------------------------------------------------------------------------
// Flash-style attention, one wave per (b,h, 16 q-rows). relu-mask -> single
// pass exp(max(s,0)); l >= S so no div hazard.
// Q,K: [B,H,S,64]; Vt: [B,H,64,S]; ctx out: [B*S, D] token-major.
// ---------------------------------------------------------------------------
__global__ __launch_bounds__(64) void attn_kernel(
    const bf16* __restrict__ Q, const bf16* __restrict__ Kb,
    const bf16* __restrict__ Vt, bf16* __restrict__ ctx) {
  const int lane = threadIdx.x;
  const int col = lane & 15, quad = lane >> 4;
  const int bh = blockIdx.y;
  const int q0 = blockIdx.x * 16;
  const bf16* Qp = Q + (size_t)bh * S_ * DH_;
  const bf16* Kp = Kb + (size_t)bh * S_ * DH_;
  const bf16* Vp = Vt + (size_t)bh * DH_ * S_;
  __shared__ alignas(16) bf16 P[16 * 32];

  s16x8 qf0 = *(const s16x8*)(Qp + (size_t)(q0 + col) * DH_ + quad * 8);
  s16x8 qf1 = *(const s16x8*)(Qp + (size_t)(q0 + col) * DH_ + 32 + quad * 8);
  const f32x4 fz = {0.f, 0.f, 0.f, 0.f};
  f32x4 accv[4];
  for (int t = 0; t < 4; t++) accv[t] = fz;
  float lpart[4] = {0.f, 0.f, 0.f, 0.f};

  for (int kt = 0; kt < S_; kt += 32) {
    const bf16* kp0 = Kp + (size_t)(kt + col) * DH_;
    const bf16* kp1 = Kp + (size_t)(kt + 16 + col) * DH_;
    s16x8 kf00 = *(const s16x8*)(kp0 + quad * 8);
    s16x8 kf01 = *(const s16x8*)(kp0 + 32 + quad * 8);
    s16x8 kf10 = *(const s16x8*)(kp1 + quad * 8);
    s16x8 kf11 = *(const s16x8*)(kp1 + 32 + quad * 8);
    f32x4 s0 = fz, s1 = fz;
    s0 = MFMA_BF16(qf0, kf00, s0);
    s0 = MFMA_BF16(qf1, kf01, s0);
    s1 = MFMA_BF16(qf0, kf10, s1);
    s1 = MFMA_BF16(qf1, kf11, s1);
    for (int r = 0; r < 4; r++) {
      float e0 = __expf(fmaxf(s0[r] * 0.125f, 0.f));
      float e1 = __expf(fmaxf(s1[r] * 0.125f, 0.f));
      lpart[r] += e0 + e1;
      P[(quad * 4 + r) * 32 + col] = __float2bfloat16(e0);
      P[(quad * 4 + r) * 32 + col + 16] = __float2bfloat16(e1);
    }
    __syncthreads();
    s16x8 pf = *(const s16x8*)(P + col * 32 + quad * 8);
    for (int t = 0; t < 4; t++) {
      s16x8 vf = *(const s16x8*)(Vp + (size_t)(t * 16 + col) * S_ + kt + quad * 8);
      accv[t] = MFMA_BF16(pf, vf, accv[t]);
    }
    __syncthreads();
  }
  for (int off = 1; off < 16; off <<= 1)
    for (int r = 0; r < 4; r++) lpart[r] += __shfl_xor(lpart[r], off, 64);
  const int b = bh >> 4, h = bh & 15;
  for (int r = 0; r < 4; r++) {
    float rl = 1.f / lpart[r];
    size_t base = (size_t)(b * S_ + q0 + quad * 4 + r) * D_ + h * DH_;
    for (int t = 0; t < 4; t++)
      ctx[base + t * 16 + col] = __float2bfloat16(accv[t][r] * rl);
  }
}

// ---------------------------------------------------------------------------
// LayerNorm over last dim (1024); bf16 out (mid) or f32 out (final).
// ---------------------------------------------------------------------------
__device__ __forceinline__ void ln_row(
    const bf16* __restrict__ x, const bf16* __restrict__ g,
    const bf16* __restrict__ b, int row, int tid, float vout[4]) {
  const int lane = tid & 63, wave = tid >> 6;
  const unsigned short* xr = (const unsigned short*)x + (size_t)row * D_;
  ushort4 xv = *(const ushort4*)(xr + tid * 4);
  float v[4];
  v[0] = bfr2f(xv.x); v[1] = bfr2f(xv.y); v[2] = bfr2f(xv.z); v[3] = bfr2f(xv.w);
  float sum = v[0] + v[1] + v[2] + v[3];
  float sq = v[0] * v[0] + v[1] * v[1] + v[2] * v[2] + v[3] * v[3];
  for (int off = 32; off > 0; off >>= 1) {
    sum += __shfl_xor(sum, off, 64);
    sq += __shfl_xor(sq, off, 64);
  }
  __shared__ float red[4][2];
  if (lane == 0) { red[wave][0] = sum; red[wave][1] = sq; }
  __syncthreads();
  sum = red[0][0] + red[1][0] + red[2][0] + red[3][0];
  sq = red[0][1] + red[1][1] + red[2][1] + red[3][1];
  float mu = sum * (1.f / D_);
  float var = sq * (1.f / D_) - mu * mu;
  float rs = rsqrtf(var + 1e-5f);
  ushort4 gv = *(const ushort4*)((const unsigned short*)g + tid * 4);
  ushort4 bv = *(const ushort4*)((const unsigned short*)b + tid * 4);
  vout[0] = (v[0] - mu) * rs * bfr2f(gv.x) + bfr2f(bv.x);
  vout[1] = (v[1] - mu) * rs * bfr2f(gv.y) + bfr2f(bv.y);
  vout[2] = (v[2] - mu) * rs * bfr2f(gv.z) + bfr2f(bv.z);
  vout[3] = (v[3] - mu) * rs * bfr2f(gv.w) + bfr2f(bv.w);
}

__global__ __launch_bounds__(256) void ln_kernel_bf16(
    const bf16* __restrict__ x, const bf16* __restrict__ g,
    const bf16* __restrict__ b, bf16* __restrict__ out) {
  const int row = blockIdx.x, tid = threadIdx.x;
  float v[4];
  ln_row(x, g, b, row, tid, v);
  ushort4 o;
  o.x = f2bfr(v[0]); o.y = f2bfr(v[1]); o.z = f2bfr(v[2]); o.w = f2bfr(v[3]);
  *(ushort4*)((unsigned short*)out + (size_t)row * D_ + tid * 4) = o;
}

__global__ __launch_bounds__(256) void ln_kernel_f32(
    const bf16* __restrict__ x, const bf16* __restrict__ g,
    const bf16* __restrict__ b, float* __restrict__ out) {
  const int row = blockIdx.x, tid = threadIdx.x;
  float v[4];
  ln_row(x, g, b, row, tid, v);
  float4 o = {v[0], v[1], v[2], v[3]};
  *(float4*)(out + (size_t)row * D_ + tid * 4) = o;
}

// ---------------------------------------------------------------------------
// Workspace (70.4 MB peak; r3 proved >=78.5 MB is available):
//   0- 8 : Xc (dead post-outproj)      -> W1c
//   8-40 : Qb(8-16) Kbf(16-24) Vt(24-32) ctx(32-40) -> hh (32 MB, contiguous)
//   40-48: z1 -> z2
//   48-56: y
//   56-64: W2c
//   64-70: Wqkv (rows 0-1023 Wq, 1024-2047 Wk, 2048-3071 Wo)
//   70-  : ln/bias vectors
// ---------------------------------------------------------------------------
extern "C" void kernel_launch(void* const* d_in, const int* in_sizes, int n_in,
                              void* d_out, int out_size, void* d_ws, size_t ws_size,
                              hipStream_t stream) {
  (void)in_sizes; (void)n_in; (void)out_size; (void)ws_size;
  const unsigned* Xs = (const unsigned*)d_in[0];

  char* ws = (char*)d_ws;
  const size_t MB = 1024 * 1024;
  bf16* Xc   = (bf16*)(ws + 0 * MB);
  bf16* W1c  = (bf16*)(ws + 0 * MB);
  bf16* Qb   = (bf16*)(ws + 8 * MB);
  bf16* Kbf  = (bf16*)(ws + 16 * MB);
  bf16* Vt   = (bf16*)(ws + 24 * MB);
  bf16* ctx  = (bf16*)(ws + 32 * MB);
  bf16* hh   = (bf16*)(ws + 8 * MB);   // 32 MB over Qb/Kbf/Vt/ctx
  bf16* z1   = (bf16*)(ws + 40 * MB);
  bf16* z2   = (bf16*)(ws + 40 * MB);
  bf16* y    = (bf16*)(ws + 48 * MB);
  bf16* W2c  = (bf16*)(ws + 56 * MB);
  bf16* Wqkv = (bf16*)(ws + 64 * MB);  // 6 MB
  bf16* ln1g = (bf16*)(ws + 70 * MB + 0 * 65536);
  bf16* ln1b = (bf16*)(ws + 70 * MB + 1 * 65536);
  bf16* ln2g = (bf16*)(ws + 70 * MB + 2 * 65536);
  bf16* ln2b = (bf16*)(ws + 70 * MB + 3 * 65536);
  bf16* b1c  = (bf16*)(ws + 70 * MB + 4 * 65536);
  bf16* b2c  = (bf16*)(ws + 70 * MB + 5 * 65536);
  bf16* Woc  = Wqkv + (size_t)2048 * D_;  // Wo rows inside Wqkv

  dim3 blk(256);
  auto conv = [&](const void* src, bf16* dst, int n) {
    convert_kernel<<<dim3((n / 4 + 255) / 256), blk, 0, stream>>>(src, Xs, dst, n);
  };

  // Phase 0: convert X, QKV weights (concatenated), vectors.
  conv(d_in[0], Xc, MTOK * D_);
  conv(d_in[1], Wqkv, D_ * D_);
  conv(d_in[2], Wqkv + (size_t)1024 * D_, D_ * D_);
  conv(d_in[3], Wqkv + (size_t)2048 * D_, D_ * D_);
  conv(d_in[4], ln1g, D_);
  conv(d_in[5], ln1b, D_);
  conv(d_in[6], ln2g, D_);
  conv(d_in[7], ln2b, D_);
  conv(d_in[9], b1c, FF_);
  conv(d_in[11], b2c, D_);

  // Phase 1: fused QKV + attention + out-proj + LN1.
  gemm_bt<<<dim3(24, 32), blk, 0, stream>>>(Xc, Wqkv, Qb, nullptr, nullptr,
                                            Kbf, Vt, MTOK, 3072, D_, 5);
  attn_kernel<<<dim3(S_ / 16, B_ * H_), dim3(64), 0, stream>>>(Qb, Kbf, Vt, ctx);
  gemm_bt<<<dim3(8, 32), blk, 0, stream>>>(ctx, Woc, z1, nullptr, Xc,
                                           nullptr, nullptr, MTOK, D_, D_, 2);
  ln_kernel_bf16<<<dim3(MTOK), blk, 0, stream>>>(z1, ln1g, ln1b, y);

  // Phase 2: FFN weights into freed slots, full-size FFN, final LN -> f32.
  conv(d_in[8], W1c, FF_ * D_);
  conv(d_in[10], W2c, D_ * FF_);
  gemm_bt<<<dim3(32, 32), blk, 0, stream>>>(y, W1c, hh, b1c, nullptr,
                                            nullptr, nullptr, MTOK, FF_, D_, 3);
  gemm_bt<<<dim3(8, 32), blk, 0, stream>>>(hh, W2c, z2, b2c, y,
                                           nullptr, nullptr, MTOK, D_, FF_, 4);
  ln_kernel_f32<<<dim3(MTOK), blk, 0, stream>>>(z2, ln2g, ln2b, (float*)d_out);
}

// Round 8
// 630.367 us; speedup vs baseline: 4.0020x; 2.3137x over previous
//
#include <hip/hip_runtime.h>
#include <hip/hip_bf16.h>

#define B_ 2
#define S_ 2048
#define D_ 1024
#define H_ 16
#define DH_ 64
#define FF_ 4096
#define MTOK 4096  // B_*S_

using bf16 = __hip_bfloat16;
typedef short s16x8 __attribute__((ext_vector_type(8)));
typedef float f32x4 __attribute__((ext_vector_type(4)));

#define MFMA_BF16(A, Bv, C) __builtin_amdgcn_mfma_f32_16x16x32_bf16(A, Bv, C, 0, 0, 0)

__device__ __forceinline__ void load_lds16(const void* g, void* l) {
  __builtin_amdgcn_global_load_lds(
      (const __attribute__((address_space(1))) void*)g,
      (__attribute__((address_space(3))) void*)l, 16, 0, 0);
}

__device__ __forceinline__ float bfr2f(unsigned short u) {
  return __uint_as_float(((unsigned)u) << 16);
}
__device__ __forceinline__ unsigned short f2bfr(float f) {
  __hip_bfloat16 h = __float2bfloat16(f);
  return *(unsigned short*)&h;
}

// ---------------------------------------------------------------------------
// Inputs are float32 (established r5->r6); sniffer kept as insurance.
// ---------------------------------------------------------------------------
__device__ int sniff_is_bf16(const unsigned* Xw) {
  int cnt = 0;
  for (int i = 0; i < 64; i++) {
    unsigned w = Xw[i];
    unsigned short h0 = (unsigned short)(w & 0xFFFF);
    unsigned short h1 = (unsigned short)(w >> 16);
    int e0 = (h0 >> 7) & 0xFF, e1 = (h1 >> 7) & 0xFF;
    if ((e0 >= 100 && e0 <= 140) || (h0 & 0x7FFF) == 0) cnt++;
    if ((e1 >= 100 && e1 <= 140) || (h1 & 0x7FFF) == 0) cnt++;
  }
  return cnt >= 110;
}

__device__ __forceinline__ void conv4(const void* src, bf16* dst, int i, int isbf) {
  ushort4 o;
  if (isbf) {
    o = *(const ushort4*)((const unsigned short*)src + i);
  } else {
    const float4 f = *(const float4*)((const float*)src + i);
    o.x = f2bfr(f.x); o.y = f2bfr(f.y); o.z = f2bfr(f.z); o.w = f2bfr(f.w);
  }
  *(ushort4*)((unsigned short*)dst + i) = o;
}

__global__ __launch_bounds__(256) void convert_kernel(
    const void* __restrict__ src, const unsigned* __restrict__ Xs,
    bf16* __restrict__ dst, int n) {
  __shared__ int isbf;
  if (threadIdx.x == 0) isbf = sniff_is_bf16(Xs);
  __syncthreads();
  int i = (blockIdx.x * 256 + threadIdx.x) * 4;
  if (i >= n) return;
  conv4(src, dst, i, isbf);
}

// three 1M-element weight tensors -> contiguous Wqkv
__global__ __launch_bounds__(256) void convert3_kernel(
    const void* __restrict__ s0, const void* __restrict__ s1,
    const void* __restrict__ s2, const unsigned* __restrict__ Xs,
    bf16* __restrict__ dst) {
  __shared__ int isbf;
  if (threadIdx.x == 0) isbf = sniff_is_bf16(Xs);
  __syncthreads();
  int i = (blockIdx.x * 256 + threadIdx.x) * 4;  // < 3*1048576
  int seg = i >> 20, loc = i & 1048575;
  const void* src = seg == 0 ? s0 : (seg == 1 ? s1 : s2);
  ushort4 o;
  if (isbf) {
    o = *(const ushort4*)((const unsigned short*)src + loc);
  } else {
    const float4 f = *(const float4*)((const float*)src + loc);
    o.x = f2bfr(f.x); o.y = f2bfr(f.y); o.z = f2bfr(f.z); o.w = f2bfr(f.w);
  }
  *(ushort4*)((unsigned short*)dst + i) = o;
}

// six small vectors -> contiguous block [ln1g|ln1b|ln2g|ln2b|b1|b2]
__global__ __launch_bounds__(256) void convertvec_kernel(
    const void* __restrict__ v0, const void* __restrict__ v1,
    const void* __restrict__ v2, const void* __restrict__ v3,
    const void* __restrict__ v4, const void* __restrict__ v5,
    const unsigned* __restrict__ Xs, bf16* __restrict__ dst) {
  __shared__ int isbf;
  if (threadIdx.x == 0) isbf = sniff_is_bf16(Xs);
  __syncthreads();
  int i = (blockIdx.x * 256 + threadIdx.x) * 4;  // < 9216
  if (i >= 9216) return;
  const void* src; int loc;
  if (i < 4096)      { int s = i >> 10; src = s == 0 ? v0 : s == 1 ? v1 : s == 2 ? v2 : v3; loc = i & 1023; }
  else if (i < 8192) { src = v4; loc = i - 4096; }
  else               { src = v5; loc = i - 8192; }
  ushort4 o;
  if (isbf) {
    o = *(const ushort4*)((const unsigned short*)src + loc);
  } else {
    const float4 f = *(const float4*)((const float*)src + loc);
    o.x = f2bfr(f.x); o.y = f2bfr(f.y); o.z = f2bfr(f.z); o.w = f2bfr(f.w);
  }
  *(ushort4*)((unsigned short*)dst + i) = o;
}

// ---------------------------------------------------------------------------
// 128x128-tile B^T GEMM.
// modes: 3 = relu(acc + bias)   (FFN1)
//        5 = fused QKV: N=3072; hx=gn>>6: <16 Q, <32 K, else V — ALL stored
//            head-major [B,H,S,DH] (coalesced 32B runs; no scatter).
// ---------------------------------------------------------------------------
__global__ __launch_bounds__(256) void gemm_bt(
    const bf16* __restrict__ A, const bf16* __restrict__ Bw,
    bf16* __restrict__ out, const bf16* __restrict__ bias,
    bf16* __restrict__ aux1, bf16* __restrict__ aux2,
    int M, int N, int K, int mode) {
  __shared__ alignas(16) bf16 As[128 * 32];
  __shared__ alignas(16) bf16 Bs[128 * 32];
  const int tid = threadIdx.x;
  const int wave = tid >> 6, lane = tid & 63;
  const int col = lane & 15, quad = lane >> 4;
  const int m0 = blockIdx.y * 128, n0 = blockIdx.x * 128;
  const int wm = (wave >> 1) * 64, wn = (wave & 1) * 64;

  const int srow = wave * 32 + (lane >> 2);
  const int skoff = (lane & 3) * 8;
  const bf16* ag = A + (size_t)(m0 + srow) * K + skoff;
  const bf16* bg = Bw + (size_t)(n0 + srow) * K + skoff;
  bf16* asl = As + wave * 1024;
  bf16* bsl = Bs + wave * 1024;

  const f32x4 fz = {0.f, 0.f, 0.f, 0.f};
  f32x4 acc[4][4];
  for (int i = 0; i < 4; i++)
    for (int j = 0; j < 4; j++) acc[i][j] = fz;

  for (int k0 = 0; k0 < K; k0 += 32) {
    load_lds16(ag + k0, asl);
    load_lds16(ag + k0 + (size_t)16 * K, asl + 512);
    load_lds16(bg + k0, bsl);
    load_lds16(bg + k0 + (size_t)16 * K, bsl + 512);
    __syncthreads();
    s16x8 Af[4], Bf[4];
    for (int t = 0; t < 4; t++) {
      Af[t] = *(const s16x8*)(As + (wm + t * 16 + col) * 32 + quad * 8);
      Bf[t] = *(const s16x8*)(Bs + (wn + t * 16 + col) * 32 + quad * 8);
    }
    for (int mt = 0; mt < 4; mt++)
      for (int nt = 0; nt < 4; nt++)
        acc[mt][nt] = MFMA_BF16(Af[mt], Bf[nt], acc[mt][nt]);
    __syncthreads();
  }

  for (int mt = 0; mt < 4; mt++) {
    for (int nt = 0; nt < 4; nt++) {
      for (int r = 0; r < 4; r++) {
        int gm = m0 + wm + mt * 16 + quad * 4 + r;
        int gn = n0 + wn + nt * 16 + col;
        float v = acc[mt][nt][r];
        if (mode == 5) {
          int b = gm >> 11, s = gm & 2047, hx = gn >> 6, dh = gn & 63;
          bf16* dst = hx < 16 ? out : (hx < 32 ? aux1 : aux2);
          int h = hx & 15;
          dst[(((size_t)(b * H_ + h) * S_ + s) << 6) + dh] = __float2bfloat16(v);
        } else {  // mode 3
          size_t idx = (size_t)gm * N + gn;
          v += __bfloat162float(bias[gn]);
          out[idx] = __float2bfloat16(fmaxf(v, 0.f));
        }
      }
    }
  }
}

// ---------------------------------------------------------------------------
// 128x64-tile B^T GEMM for N=1024 GEMMs (2 blocks/CU at 512-block grids).
// modes: 2 = acc + res (out-proj);  4 = acc + bias + res (FFN2)
// ---------------------------------------------------------------------------
__global__ __launch_bounds__(256) void gemm64(
    const bf16* __restrict__ A, const bf16* __restrict__ Bw,
    bf16* __restrict__ out, const bf16* __restrict__ bias,
    const bf16* __restrict__ res, int M, int N, int K, int mode) {
  __shared__ alignas(16) bf16 As[128 * 32];
  __shared__ alignas(16) bf16 Bs[64 * 32];
  const int tid = threadIdx.x;
  const int wave = tid >> 6, lane = tid & 63;
  const int col = lane & 15, quad = lane >> 4;
  const int m0 = blockIdx.y * 128, n0 = blockIdx.x * 64;
  const int wm = (wave >> 1) * 64, wn = (wave & 1) * 32;

  const int srowA = wave * 32 + (lane >> 2);
  const int srowB = wave * 16 + (lane >> 2);
  const int skoff = (lane & 3) * 8;
  const bf16* ag = A + (size_t)(m0 + srowA) * K + skoff;
  const bf16* bg = Bw + (size_t)(n0 + srowB) * K + skoff;
  bf16* asl = As + wave * 1024;
  bf16* bsl = Bs + wave * 512;

  const f32x4 fz = {0.f, 0.f, 0.f, 0.f};
  f32x4 acc[4][2];
  for (int i = 0; i < 4; i++)
    for (int j = 0; j < 2; j++) acc[i][j] = fz;

  for (int k0 = 0; k0 < K; k0 += 32) {
    load_lds16(ag + k0, asl);
    load_lds16(ag + k0 + (size_t)16 * K, asl + 512);
    load_lds16(bg + k0, bsl);
    __syncthreads();
    s16x8 Af[4], Bf[2];
    for (int t = 0; t < 4; t++)
      Af[t] = *(const s16x8*)(As + (wm + t * 16 + col) * 32 + quad * 8);
    for (int t = 0; t < 2; t++)
      Bf[t] = *(const s16x8*)(Bs + (wn + t * 16 + col) * 32 + quad * 8);
    for (int mt = 0; mt < 4; mt++)
      for (int nt = 0; nt < 2; nt++)
        acc[mt][nt] = MFMA_BF16(Af[mt], Bf[nt], acc[mt][nt]);
    __syncthreads();
  }

  for (int mt = 0; mt < 4; mt++) {
    for (int nt = 0; nt < 2; nt++) {
      for (int r = 0; r < 4; r++) {
        int gm = m0 + wm + mt * 16 + quad * 4 + r;
        int gn = n0 + wn + nt * 16 + col;
        float v = acc[mt][nt][r];
        size_t idx = (size_t)gm * N + gn;
        if (mode == 2) {
          v += __bfloat162float(res[idx]);
        } else {  // mode 4
          v += __bfloat162float(bias[gn]) + __bfloat162float(res[idx]);
        }
        out[idx] = __float2bfloat16(v);
      }
    }
  }
}

// ---------------------------------------------------------------------------
// V head-major -> Vt [B,H,DH,S] transpose, 64x64 LDS tiles, coalesced I/O.
// grid (S/64, B*H), 256 threads.
// ---------------------------------------------------------------------------
__global__ __launch_bounds__(256) void tpose_v(
    const bf16* __restrict__ Vb, bf16* __restrict__ Vt) {
  __shared__ unsigned short Ts[64][72];
  const int tid = threadIdx.x;
  const int bh = blockIdx.y, kt = blockIdx.x;
  const unsigned short* in =
      (const unsigned short*)Vb + (((size_t)bh * S_ + kt * 64) << 6);
  unsigned short* outp =
      (unsigned short*)Vt + ((size_t)bh << 17) + kt * 64;

  const int r = tid >> 2, cc = (tid & 3) * 16;
  s16x8 a = *(const s16x8*)(in + r * 64 + cc);
  s16x8 b = *(const s16x8*)(in + r * 64 + cc + 8);
  for (int j = 0; j < 8; j++) Ts[cc + j][r] = (unsigned short)a[j];
  for (int j = 0; j < 8; j++) Ts[cc + 8 + j][r] = (unsigned short)b[j];
  __syncthreads();
  const int dh = tid >> 2, sc = (tid & 3) * 16;
  s16x8 o0, o1;
  for (int j = 0; j < 8; j++) o0[j] = (short)Ts[dh][sc + j];
  for (int j = 0; j < 8; j++) o1[j] = (short)Ts[dh][sc + 8 + j];
  *(s16x8*)(outp + (size_t)dh * S_ + sc) = o0;
  *(s16x8*)(outp + (size_t)dh * S_ + sc + 8) = o1;
}

// ---------------------------------------------------------------------------
// Flash-style attention (unchanged): one wave per (b,h, 16 q-rows).
// Q,K: [B,H,S,64]; Vt: [B,H,64,S]; ctx out: [B*S, D] token-major.
// ---------------------------------------------------------------------------
__global__ __launch_bounds__(64) void attn_kernel(
    const bf16* __restrict__ Q, const bf16* __restrict__ Kb,
    const bf16* __restrict__ Vt, bf16* __restrict__ ctx) {
  const int lane = threadIdx.x;
  const int col = lane & 15, quad = lane >> 4;
  const int bh = blockIdx.y;
  const int q0 = blockIdx.x * 16;
  const bf16* Qp = Q + (size_t)bh * S_ * DH_;
  const bf16* Kp = Kb + (size_t)bh * S_ * DH_;
  const bf16* Vp = Vt + (size_t)bh * DH_ * S_;
  __shared__ alignas(16) bf16 P[16 * 32];

  s16x8 qf0 = *(const s16x8*)(Qp + (size_t)(q0 + col) * DH_ + quad * 8);
  s16x8 qf1 = *(const s16x8*)(Qp + (size_t)(q0 + col) * DH_ + 32 + quad * 8);
  const f32x4 fz = {0.f, 0.f, 0.f, 0.f};
  f32x4 accv[4];
  for (int t = 0; t < 4; t++) accv[t] = fz;
  float lpart[4] = {0.f, 0.f, 0.f, 0.f};

  for (int kt = 0; kt < S_; kt += 32) {
    const bf16* kp0 = Kp + (size_t)(kt + col) * DH_;
    const bf16* kp1 = Kp + (size_t)(kt + 16 + col) * DH_;
    s16x8 kf00 = *(const s16x8*)(kp0 + quad * 8);
    s16x8 kf01 = *(const s16x8*)(kp0 + 32 + quad * 8);
    s16x8 kf10 = *(const s16x8*)(kp1 + quad * 8);
    s16x8 kf11 = *(const s16x8*)(kp1 + 32 + quad * 8);
    f32x4 s0 = fz, s1 = fz;
    s0 = MFMA_BF16(qf0, kf00, s0);
    s0 = MFMA_BF16(qf1, kf01, s0);
    s1 = MFMA_BF16(qf0, kf10, s1);
    s1 = MFMA_BF16(qf1, kf11, s1);
    for (int r = 0; r < 4; r++) {
      float e0 = __expf(fmaxf(s0[r] * 0.125f, 0.f));
      float e1 = __expf(fmaxf(s1[r] * 0.125f, 0.f));
      lpart[r] += e0 + e1;
      P[(quad * 4 + r) * 32 + col] = __float2bfloat16(e0);
      P[(quad * 4 + r) * 32 + col + 16] = __float2bfloat16(e1);
    }
    __syncthreads();
    s16x8 pf = *(const s16x8*)(P + col * 32 + quad * 8);
    for (int t = 0; t < 4; t++) {
      s16x8 vf = *(const s16x8*)(Vp + (size_t)(t * 16 + col) * S_ + kt + quad * 8);
      accv[t] = MFMA_BF16(pf, vf, accv[t]);
    }
    __syncthreads();
  }
  for (int off = 1; off < 16; off <<= 1)
    for (int r = 0; r < 4; r++) lpart[r] += __shfl_xor(lpart[r], off, 64);
  const int b = bh >> 4, h = bh & 15;
  for (int r = 0; r < 4; r++) {
    float rl = 1.f / lpart[r];
    size_t base = (size_t)(b * S_ + q0 + quad * 4 + r) * D_ + h * DH_;
    for (int t = 0; t < 4; t++)
      ctx[base + t * 16 + col] = __float2bfloat16(accv[t][r] * rl);
  }
}

// ---------------------------------------------------------------------------
// LayerNorm over last dim (1024); bf16 out (mid) or f32 out (final).
// ---------------------------------------------------------------------------
__device__ __forceinline__ void ln_row(
    const bf16* __restrict__ x, const bf16* __restrict__ g,
    const bf16* __restrict__ b, int row, int tid, float vout[4]) {
  const int lane = tid & 63, wave = tid >> 6;
  const unsigned short* xr = (const unsigned short*)x + (size_t)row * D_;
  ushort4 xv = *(const ushort4*)(xr + tid * 4);
  float v[4];
  v[0] = bfr2f(xv.x); v[1] = bfr2f(xv.y); v[2] = bfr2f(xv.z); v[3] = bfr2f(xv.w);
  float sum = v[0] + v[1] + v[2] + v[3];
  float sq = v[0] * v[0] + v[1] * v[1] + v[2] * v[2] + v[3] * v[3];
  for (int off = 32; off > 0; off >>= 1) {
    sum += __shfl_xor(sum, off, 64);
    sq += __shfl_xor(sq, off, 64);
  }
  __shared__ float red[4][2];
  if (lane == 0) { red[wave][0] = sum; red[wave][1] = sq; }
  __syncthreads();
  sum = red[0][0] + red[1][0] + red[2][0] + red[3][0];
  sq = red[0][1] + red[1][1] + red[2][1] + red[3][1];
  float mu = sum * (1.f / D_);
  float var = sq * (1.f / D_) - mu * mu;
  float rs = rsqrtf(var + 1e-5f);
  ushort4 gv = *(const ushort4*)((const unsigned short*)g + tid * 4);
  ushort4 bv = *(const ushort4*)((const unsigned short*)b + tid * 4);
  vout[0] = (v[0] - mu) * rs * bfr2f(gv.x) + bfr2f(bv.x);
  vout[1] = (v[1] - mu) * rs * bfr2f(gv.y) + bfr2f(bv.y);
  vout[2] = (v[2] - mu) * rs * bfr2f(gv.z) + bfr2f(bv.z);
  vout[3] = (v[3] - mu) * rs * bfr2f(gv.w) + bfr2f(bv.w);
}

__global__ __launch_bounds__(256) void ln_kernel_bf16(
    const bf16* __restrict__ x, const bf16* __restrict__ g,
    const bf16* __restrict__ b, bf16* __restrict__ out) {
  const int row = blockIdx.x, tid = threadIdx.x;
  float v[4];
  ln_row(x, g, b, row, tid, v);
  ushort4 o;
  o.x = f2bfr(v[0]); o.y = f2bfr(v[1]); o.z = f2bfr(v[2]); o.w = f2bfr(v[3]);
  *(ushort4*)((unsigned short*)out + (size_t)row * D_ + tid * 4) = o;
}

__global__ __launch_bounds__(256) void ln_kernel_f32(
    const bf16* __restrict__ x, const bf16* __restrict__ g,
    const bf16* __restrict__ b, float* __restrict__ out) {
  const int row = blockIdx.x, tid = threadIdx.x;
  float v[4];
  ln_row(x, g, b, row, tid, v);
  float4 o = {v[0], v[1], v[2], v[3]};
  *(float4*)(out + (size_t)row * D_ + tid * 4) = o;
}

// ---------------------------------------------------------------------------
// Workspace (70.4 MB peak; ws_size >= 78.5 MB established r3):
//   0- 8 : Xc -> W1c
//   8-16 : Qb -> z1 -> z2
//   16-24: Kbf -> y
//   24-32: Vb -> W2c
//   32-40: Vt  \
//   40-48: ctx  |-> hh (32-64, 32 MB)
//   48-64: (hh) /
//   64-70: Wqkv;  70-: vectors [ln1g|ln1b|ln2g|ln2b|b1|b2]
// ---------------------------------------------------------------------------
extern "C" void kernel_launch(void* const* d_in, const int* in_sizes, int n_in,
                              void* d_out, int out_size, void* d_ws, size_t ws_size,
                              hipStream_t stream) {
  (void)in_sizes; (void)n_in; (void)out_size; (void)ws_size;
  const unsigned* Xs = (const unsigned*)d_in[0];

  char* ws = (char*)d_ws;
  const size_t MB = 1024 * 1024;
  bf16* Xc   = (bf16*)(ws + 0 * MB);
  bf16* W1c  = (bf16*)(ws + 0 * MB);
  bf16* Qb   = (bf16*)(ws + 8 * MB);
  bf16* z1   = (bf16*)(ws + 8 * MB);
  bf16* z2   = (bf16*)(ws + 8 * MB);
  bf16* Kbf  = (bf16*)(ws + 16 * MB);
  bf16* y    = (bf16*)(ws + 16 * MB);
  bf16* Vb   = (bf16*)(ws + 24 * MB);
  bf16* W2c  = (bf16*)(ws + 24 * MB);
  bf16* Vt   = (bf16*)(ws + 32 * MB);
  bf16* hh   = (bf16*)(ws + 32 * MB);  // 32 MB (over Vt/ctx/fresh)
  bf16* ctx  = (bf16*)(ws + 40 * MB);
  bf16* Wqkv = (bf16*)(ws + 64 * MB);
  bf16* vecs = (bf16*)(ws + 70 * MB);
  bf16* ln1g = vecs + 0;
  bf16* ln1b = vecs + 1024;
  bf16* ln2g = vecs + 2048;
  bf16* ln2b = vecs + 3072;
  bf16* b1c  = vecs + 4096;
  bf16* b2c  = vecs + 8192;
  bf16* Woc  = Wqkv + (size_t)2048 * D_;

  dim3 blk(256);
  // Phase 0: conversions (3 launches for phase-1 needs).
  convert_kernel<<<dim3(MTOK * D_ / 1024), blk, 0, stream>>>(d_in[0], Xs, Xc, MTOK * D_);
  convert3_kernel<<<dim3(3072), blk, 0, stream>>>(d_in[1], d_in[2], d_in[3], Xs, Wqkv);
  convertvec_kernel<<<dim3(9), blk, 0, stream>>>(d_in[4], d_in[5], d_in[6], d_in[7],
                                                 d_in[9], d_in[11], Xs, vecs);

  // Phase 1: fused QKV (all head-major) + V transpose + attention + out-proj + LN1.
  gemm_bt<<<dim3(24, 32), blk, 0, stream>>>(Xc, Wqkv, Qb, nullptr, Kbf, Vb,
                                            MTOK, 3072, D_, 5);
  tpose_v<<<dim3(S_ / 64, B_ * H_), blk, 0, stream>>>(Vb, Vt);
  attn_kernel<<<dim3(S_ / 16, B_ * H_), dim3(64), 0, stream>>>(Qb, Kbf, Vt, ctx);
  gemm64<<<dim3(16, 32), blk, 0, stream>>>(ctx, Woc, z1, nullptr, Xc, MTOK, D_, D_, 2);
  ln_kernel_bf16<<<dim3(MTOK), blk, 0, stream>>>(z1, ln1g, ln1b, y);

  // Phase 2: FFN weights into freed slots, FFN, final LN -> f32 out.
  convert_kernel<<<dim3(FF_ * D_ / 1024), blk, 0, stream>>>(d_in[8], Xs, W1c, FF_ * D_);
  convert_kernel<<<dim3(D_ * FF_ / 1024), blk, 0, stream>>>(d_in[10], Xs, W2c, D_ * FF_);
  gemm_bt<<<dim3(32, 32), blk, 0, stream>>>(y, W1c, hh, b1c, nullptr, nullptr,
                                            MTOK, FF_, D_, 3);
  gemm64<<<dim3(16, 32), blk, 0, stream>>>(hh, W2c, z2, b2c, y, MTOK, D_, FF_, 4);
  ln_kernel_f32<<<dim3(MTOK), blk, 0, stream>>>(z2, ln2g, ln2b, (float*)d_out);
}

// Round 9
// 473.959 us; speedup vs baseline: 5.3226x; 1.3300x over previous
//
#include <hip/hip_runtime.h>
#include <hip/hip_bf16.h>

#define B_ 2
#define S_ 2048
#define D_ 1024
#define H_ 16
#define DH_ 64
#define FF_ 4096
#define MTOK 4096  // B_*S_

using bf16 = __hip_bfloat16;
typedef short s16x8 __attribute__((ext_vector_type(8)));
typedef float f32x4 __attribute__((ext_vector_type(4)));

#define MFMA_BF16(A, Bv, C) __builtin_amdgcn_mfma_f32_16x16x32_bf16(A, Bv, C, 0, 0, 0)

__device__ __forceinline__ void load_lds16(const void* g, void* l) {
  __builtin_amdgcn_global_load_lds(
      (const __attribute__((address_space(1))) void*)g,
      (__attribute__((address_space(3))) void*)l, 16, 0, 0);
}

__device__ __forceinline__ float bfr2f(unsigned short u) {
  return __uint_as_float(((unsigned)u) << 16);
}
__device__ __forceinline__ unsigned short f2bfr(float f) {
  __hip_bfloat16 h = __float2bfloat16(f);
  return *(unsigned short*)&h;
}

// ---------------------------------------------------------------------------
// Inputs are float32 (established r5->r6); sniffer kept as insurance.
// ---------------------------------------------------------------------------
__device__ int sniff_is_bf16(const unsigned* Xw) {
  int cnt = 0;
  for (int i = 0; i < 64; i++) {
    unsigned w = Xw[i];
    unsigned short h0 = (unsigned short)(w & 0xFFFF);
    unsigned short h1 = (unsigned short)(w >> 16);
    int e0 = (h0 >> 7) & 0xFF, e1 = (h1 >> 7) & 0xFF;
    if ((e0 >= 100 && e0 <= 140) || (h0 & 0x7FFF) == 0) cnt++;
    if ((e1 >= 100 && e1 <= 140) || (h1 & 0x7FFF) == 0) cnt++;
  }
  return cnt >= 110;
}

__device__ __forceinline__ void conv4(const void* src, bf16* dst, int i, int isbf) {
  ushort4 o;
  if (isbf) {
    o = *(const ushort4*)((const unsigned short*)src + i);
  } else {
    const float4 f = *(const float4*)((const float*)src + i);
    o.x = f2bfr(f.x); o.y = f2bfr(f.y); o.z = f2bfr(f.z); o.w = f2bfr(f.w);
  }
  *(ushort4*)((unsigned short*)dst + i) = o;
}

__global__ __launch_bounds__(256) void convert_kernel(
    const void* __restrict__ src, const unsigned* __restrict__ Xs,
    bf16* __restrict__ dst, int n) {
  __shared__ int isbf;
  if (threadIdx.x == 0) isbf = sniff_is_bf16(Xs);
  __syncthreads();
  int i = (blockIdx.x * 256 + threadIdx.x) * 4;
  if (i >= n) return;
  conv4(src, dst, i, isbf);
}

// three 1M-element weight tensors -> contiguous Wqkv
__global__ __launch_bounds__(256) void convert3_kernel(
    const void* __restrict__ s0, const void* __restrict__ s1,
    const void* __restrict__ s2, const unsigned* __restrict__ Xs,
    bf16* __restrict__ dst) {
  __shared__ int isbf;
  if (threadIdx.x == 0) isbf = sniff_is_bf16(Xs);
  __syncthreads();
  int i = (blockIdx.x * 256 + threadIdx.x) * 4;  // < 3*1048576
  int seg = i >> 20, loc = i & 1048575;
  const void* src = seg == 0 ? s0 : (seg == 1 ? s1 : s2);
  ushort4 o;
  if (isbf) {
    o = *(const ushort4*)((const unsigned short*)src + loc);
  } else {
    const float4 f = *(const float4*)((const float*)src + loc);
    o.x = f2bfr(f.x); o.y = f2bfr(f.y); o.z = f2bfr(f.z); o.w = f2bfr(f.w);
  }
  *(ushort4*)((unsigned short*)dst + i) = o;
}

// six small vectors -> contiguous block [ln1g|ln1b|ln2g|ln2b|b1|b2]
__global__ __launch_bounds__(256) void convertvec_kernel(
    const void* __restrict__ v0, const void* __restrict__ v1,
    const void* __restrict__ v2, const void* __restrict__ v3,
    const void* __restrict__ v4, const void* __restrict__ v5,
    const unsigned* __restrict__ Xs, bf16* __restrict__ dst) {
  __shared__ int isbf;
  if (threadIdx.x == 0) isbf = sniff_is_bf16(Xs);
  __syncthreads();
  int i = (blockIdx.x * 256 + threadIdx.x) * 4;  // < 9216
  if (i >= 9216) return;
  const void* src; int loc;
  if (i < 4096)      { int s = i >> 10; src = s == 0 ? v0 : s == 1 ? v1 : s == 2 ? v2 : v3; loc = i & 1023; }
  else if (i < 8192) { src = v4; loc = i - 4096; }
  else               { src = v5; loc = i - 8192; }
  ushort4 o;
  if (isbf) {
    o = *(const ushort4*)((const unsigned short*)src + loc);
  } else {
    const float4 f = *(const float4*)((const float*)src + loc);
    o.x = f2bfr(f.x); o.y = f2bfr(f.y); o.z = f2bfr(f.z); o.w = f2bfr(f.w);
  }
  *(ushort4*)((unsigned short*)dst + i) = o;
}

// ---------------------------------------------------------------------------
// 128x128-tile B^T GEMM.
// modes: 3 = relu(acc + bias)   (FFN1)
//        5 = fused QKV: N=3072; hx=gn>>6: <16 Q, <32 K, else V — all head-major
// ---------------------------------------------------------------------------
__global__ __launch_bounds__(256) void gemm_bt(
    const bf16* __restrict__ A, const bf16* __restrict__ Bw,
    bf16* __restrict__ out, const bf16* __restrict__ bias,
    bf16* __restrict__ aux1, bf16* __restrict__ aux2,
    int M, int N, int K, int mode) {
  __shared__ alignas(16) bf16 As[128 * 32];
  __shared__ alignas(16) bf16 Bs[128 * 32];
  const int tid = threadIdx.x;
  const int wave = tid >> 6, lane = tid & 63;
  const int col = lane & 15, quad = lane >> 4;
  const int m0 = blockIdx.y * 128, n0 = blockIdx.x * 128;
  const int wm = (wave >> 1) * 64, wn = (wave & 1) * 64;

  const int srow = wave * 32 + (lane >> 2);
  const int skoff = (lane & 3) * 8;
  const bf16* ag = A + (size_t)(m0 + srow) * K + skoff;
  const bf16* bg = Bw + (size_t)(n0 + srow) * K + skoff;
  bf16* asl = As + wave * 1024;
  bf16* bsl = Bs + wave * 1024;

  const f32x4 fz = {0.f, 0.f, 0.f, 0.f};
  f32x4 acc[4][4];
  for (int i = 0; i < 4; i++)
    for (int j = 0; j < 4; j++) acc[i][j] = fz;

  for (int k0 = 0; k0 < K; k0 += 32) {
    load_lds16(ag + k0, asl);
    load_lds16(ag + k0 + (size_t)16 * K, asl + 512);
    load_lds16(bg + k0, bsl);
    load_lds16(bg + k0 + (size_t)16 * K, bsl + 512);
    __syncthreads();
    s16x8 Af[4], Bf[4];
    for (int t = 0; t < 4; t++) {
      Af[t] = *(const s16x8*)(As + (wm + t * 16 + col) * 32 + quad * 8);
      Bf[t] = *(const s16x8*)(Bs + (wn + t * 16 + col) * 32 + quad * 8);
    }
    for (int mt = 0; mt < 4; mt++)
      for (int nt = 0; nt < 4; nt++)
        acc[mt][nt] = MFMA_BF16(Af[mt], Bf[nt], acc[mt][nt]);
    __syncthreads();
  }

  for (int mt = 0; mt < 4; mt++) {
    for (int nt = 0; nt < 4; nt++) {
      for (int r = 0; r < 4; r++) {
        int gm = m0 + wm + mt * 16 + quad * 4 + r;
        int gn = n0 + wn + nt * 16 + col;
        float v = acc[mt][nt][r];
        if (mode == 5) {
          int b = gm >> 11, s = gm & 2047, hx = gn >> 6, dh = gn & 63;
          bf16* dst = hx < 16 ? out : (hx < 32 ? aux1 : aux2);
          int h = hx & 15;
          dst[(((size_t)(b * H_ + h) * S_ + s) << 6) + dh] = __float2bfloat16(v);
        } else {  // mode 3
          size_t idx = (size_t)gm * N + gn;
          v += __bfloat162float(bias[gn]);
          out[idx] = __float2bfloat16(fmaxf(v, 0.f));
        }
      }
    }
  }
}

// ---------------------------------------------------------------------------
// 128x64-tile B^T GEMM for N=1024 GEMMs (512-block grids, 2 blocks/CU).
// modes: 2 = acc + res (out-proj);  4 = acc + bias + res (FFN2)
// ---------------------------------------------------------------------------
__global__ __launch_bounds__(256) void gemm64(
    const bf16* __restrict__ A, const bf16* __restrict__ Bw,
    bf16* __restrict__ out, const bf16* __restrict__ bias,
    const bf16* __restrict__ res, int M, int N, int K, int mode) {
  __shared__ alignas(16) bf16 As[128 * 32];
  __shared__ alignas(16) bf16 Bs[64 * 32];
  const int tid = threadIdx.x;
  const int wave = tid >> 6, lane = tid & 63;
  const int col = lane & 15, quad = lane >> 4;
  const int m0 = blockIdx.y * 128, n0 = blockIdx.x * 64;
  const int wm = (wave >> 1) * 64, wn = (wave & 1) * 32;

  const int srowA = wave * 32 + (lane >> 2);
  const int srowB = wave * 16 + (lane >> 2);
  const int skoff = (lane & 3) * 8;
  const bf16* ag = A + (size_t)(m0 + srowA) * K + skoff;
  const bf16* bg = Bw + (size_t)(n0 + srowB) * K + skoff;
  bf16* asl = As + wave * 1024;
  bf16* bsl = Bs + wave * 512;

  const f32x4 fz = {0.f, 0.f, 0.f, 0.f};
  f32x4 acc[4][2];
  for (int i = 0; i < 4; i++)
    for (int j = 0; j < 2; j++) acc[i][j] = fz;

  for (int k0 = 0; k0 < K; k0 += 32) {
    load_lds16(ag + k0, asl);
    load_lds16(ag + k0 + (size_t)16 * K, asl + 512);
    load_lds16(bg + k0, bsl);
    __syncthreads();
    s16x8 Af[4], Bf[2];
    for (int t = 0; t < 4; t++)
      Af[t] = *(const s16x8*)(As + (wm + t * 16 + col) * 32 + quad * 8);
    for (int t = 0; t < 2; t++)
      Bf[t] = *(const s16x8*)(Bs + (wn + t * 16 + col) * 32 + quad * 8);
    for (int mt = 0; mt < 4; mt++)
      for (int nt = 0; nt < 2; nt++)
        acc[mt][nt] = MFMA_BF16(Af[mt], Bf[nt], acc[mt][nt]);
    __syncthreads();
  }

  for (int mt = 0; mt < 4; mt++) {
    for (int nt = 0; nt < 2; nt++) {
      for (int r = 0; r < 4; r++) {
        int gm = m0 + wm + mt * 16 + quad * 4 + r;
        int gn = n0 + wn + nt * 16 + col;
        float v = acc[mt][nt][r];
        size_t idx = (size_t)gm * N + gn;
        if (mode == 2) {
          v += __bfloat162float(res[idx]);
        } else {  // mode 4
          v += __bfloat162float(bias[gn]) + __bfloat162float(res[idx]);
        }
        out[idx] = __float2bfloat16(v);
      }
    }
  }
}

// ---------------------------------------------------------------------------
// V head-major -> Vt [B,H,DH,S] transpose, 64x64 LDS tiles, coalesced I/O.
// ---------------------------------------------------------------------------
__global__ __launch_bounds__(256) void tpose_v(
    const bf16* __restrict__ Vb, bf16* __restrict__ Vt) {
  __shared__ unsigned short Ts[64][72];
  const int tid = threadIdx.x;
  const int bh = blockIdx.y, kt = blockIdx.x;
  const unsigned short* in =
      (const unsigned short*)Vb + (((size_t)bh * S_ + kt * 64) << 6);
  unsigned short* outp =
      (unsigned short*)Vt + ((size_t)bh << 17) + kt * 64;

  const int r = tid >> 2, cc = (tid & 3) * 16;
  s16x8 a = *(const s16x8*)(in + r * 64 + cc);
  s16x8 b = *(const s16x8*)(in + r * 64 + cc + 8);
  for (int j = 0; j < 8; j++) Ts[cc + j][r] = (unsigned short)a[j];
  for (int j = 0; j < 8; j++) Ts[cc + 8 + j][r] = (unsigned short)b[j];
  __syncthreads();
  const int dh = tid >> 2, sc = (tid & 3) * 16;
  s16x8 o0, o1;
  for (int j = 0; j < 8; j++) o0[j] = (short)Ts[dh][sc + j];
  for (int j = 0; j < 8; j++) o1[j] = (short)Ts[dh][sc + 8 + j];
  *(s16x8*)(outp + (size_t)dh * S_ + sc) = o0;
  *(s16x8*)(outp + (size_t)dh * S_ + sc + 8) = o1;
}

// ---------------------------------------------------------------------------
// Tiled flash attention: 256 threads (4 waves), 64 q-rows per block, grid
// (S/64, B*H). Per 64-key tile: K[64key][64dh] and Vt[64dh][64key] staged in
// LDS (stride-72 pad -> <=2-way conflicts), each wave computes its 16 q-rows.
// relu-mask -> single-pass exp(max(s,0)); l >= S so no div hazard.
// P is per-wave LDS (C-layout -> A-layout round trip, same-wave only).
// ---------------------------------------------------------------------------
__global__ __launch_bounds__(256) void attn_kernel(
    const bf16* __restrict__ Q, const bf16* __restrict__ Kb,
    const bf16* __restrict__ Vt, bf16* __restrict__ ctx) {
  __shared__ alignas(16) unsigned short Ks[64 * 72];
  __shared__ alignas(16) unsigned short Vs[64 * 72];
  __shared__ alignas(16) unsigned short Ps[4][16 * 72];
  const int tid = threadIdx.x;
  const int wave = tid >> 6, lane = tid & 63;
  const int col = lane & 15, quad = lane >> 4;
  const int bh = blockIdx.y;
  const int q0 = blockIdx.x * 64 + wave * 16;
  const bf16* Qp = Q + (size_t)bh * S_ * DH_;
  const bf16* Kp = Kb + (size_t)bh * S_ * DH_;
  const bf16* Vp = Vt + (size_t)bh * DH_ * S_;
  unsigned short* Pw = Ps[wave];

  // Q A-frags: m=lane&15, k=quad*8+j; two 32-wide k-chunks
  s16x8 qf0 = *(const s16x8*)(Qp + (size_t)(q0 + col) * DH_ + quad * 8);
  s16x8 qf1 = *(const s16x8*)(Qp + (size_t)(q0 + col) * DH_ + 32 + quad * 8);

  const f32x4 fz = {0.f, 0.f, 0.f, 0.f};
  f32x4 accv[4];
  for (int t = 0; t < 4; t++) accv[t] = fz;
  float lpart[4] = {0.f, 0.f, 0.f, 0.f};

  const int srow = tid >> 2, sseg = (tid & 3) * 16;  // staging: 4 thr/row

  for (int kt = 0; kt < S_; kt += 64) {
    // load next tiles to regs (issues before barrier wait)
    s16x8 k0 = *(const s16x8*)(Kp + (size_t)(kt + srow) * DH_ + sseg);
    s16x8 k1 = *(const s16x8*)(Kp + (size_t)(kt + srow) * DH_ + sseg + 8);
    s16x8 v0 = *(const s16x8*)(Vp + (size_t)srow * S_ + kt + sseg);
    s16x8 v1 = *(const s16x8*)(Vp + (size_t)srow * S_ + kt + sseg + 8);
    __syncthreads();  // prior tile fully consumed
    *(s16x8*)(Ks + srow * 72 + sseg) = k0;
    *(s16x8*)(Ks + srow * 72 + sseg + 8) = k1;
    *(s16x8*)(Vs + srow * 72 + sseg) = v0;
    *(s16x8*)(Vs + srow * 72 + sseg + 8) = v1;
    __syncthreads();  // tiles staged

    // QK^T + exp -> P  (4 key n-tiles)
    for (int t = 0; t < 4; t++) {
      s16x8 kf0 = *(const s16x8*)(Ks + (t * 16 + col) * 72 + quad * 8);
      s16x8 kf1 = *(const s16x8*)(Ks + (t * 16 + col) * 72 + 32 + quad * 8);
      f32x4 s = fz;
      s = MFMA_BF16(qf0, kf0, s);
      s = MFMA_BF16(qf1, kf1, s);
      for (int r = 0; r < 4; r++) {
        float e = __expf(fmaxf(s[r] * 0.125f, 0.f));
        lpart[r] += e;
        Pw[(quad * 4 + r) * 72 + t * 16 + col] = f2bfr(e);
      }
    }
    // P A-frags (same-wave write->read; compiler inserts lgkm wait)
    s16x8 pf0 = *(const s16x8*)(Pw + col * 72 + quad * 8);
    s16x8 pf1 = *(const s16x8*)(Pw + col * 72 + 32 + quad * 8);
    for (int t = 0; t < 4; t++) {
      s16x8 vf0 = *(const s16x8*)(Vs + (t * 16 + col) * 72 + quad * 8);
      s16x8 vf1 = *(const s16x8*)(Vs + (t * 16 + col) * 72 + 32 + quad * 8);
      accv[t] = MFMA_BF16(pf0, vf0, accv[t]);
      accv[t] = MFMA_BF16(pf1, vf1, accv[t]);
    }
  }

  // reduce l over the 16 key-columns (lanes within quad group)
  for (int off = 1; off < 16; off <<= 1)
    for (int r = 0; r < 4; r++) lpart[r] += __shfl_xor(lpart[r], off, 64);
  const int b = bh >> 4, h = bh & 15;
  for (int r = 0; r < 4; r++) {
    float rl = 1.f / lpart[r];
    size_t base = (size_t)(b * S_ + q0 + quad * 4 + r) * D_ + h * DH_;
    for (int t = 0; t < 4; t++)
      ctx[base + t * 16 + col] = __float2bfloat16(accv[t][r] * rl);
  }
}

// ---------------------------------------------------------------------------
// LayerNorm over last dim (1024); bf16 out (mid) or f32 out (final).
// ---------------------------------------------------------------------------
__device__ __forceinline__ void ln_row(
    const bf16* __restrict__ x, const bf16* __restrict__ g,
    const bf16* __restrict__ b, int row, int tid, float vout[4]) {
  const int lane = tid & 63, wave = tid >> 6;
  const unsigned short* xr = (const unsigned short*)x + (size_t)row * D_;
  ushort4 xv = *(const ushort4*)(xr + tid * 4);
  float v[4];
  v[0] = bfr2f(xv.x); v[1] = bfr2f(xv.y); v[2] = bfr2f(xv.z); v[3] = bfr2f(xv.w);
  float sum = v[0] + v[1] + v[2] + v[3];
  float sq = v[0] * v[0] + v[1] * v[1] + v[2] * v[2] + v[3] * v[3];
  for (int off = 32; off > 0; off >>= 1) {
    sum += __shfl_xor(sum, off, 64);
    sq += __shfl_xor(sq, off, 64);
  }
  __shared__ float red[4][2];
  if (lane == 0) { red[wave][0] = sum; red[wave][1] = sq; }
  __syncthreads();
  sum = red[0][0] + red[1][0] + red[2][0] + red[3][0];
  sq = red[0][1] + red[1][1] + red[2][1] + red[3][1];
  float mu = sum * (1.f / D_);
  float var = sq * (1.f / D_) - mu * mu;
  float rs = rsqrtf(var + 1e-5f);
  ushort4 gv = *(const ushort4*)((const unsigned short*)g + tid * 4);
  ushort4 bv = *(const ushort4*)((const unsigned short*)b + tid * 4);
  vout[0] = (v[0] - mu) * rs * bfr2f(gv.x) + bfr2f(bv.x);
  vout[1] = (v[1] - mu) * rs * bfr2f(gv.y) + bfr2f(bv.y);
  vout[2] = (v[2] - mu) * rs * bfr2f(gv.z) + bfr2f(bv.z);
  vout[3] = (v[3] - mu) * rs * bfr2f(gv.w) + bfr2f(bv.w);
}

__global__ __launch_bounds__(256) void ln_kernel_bf16(
    const bf16* __restrict__ x, const bf16* __restrict__ g,
    const bf16* __restrict__ b, bf16* __restrict__ out) {
  const int row = blockIdx.x, tid = threadIdx.x;
  float v[4];
  ln_row(x, g, b, row, tid, v);
  ushort4 o;
  o.x = f2bfr(v[0]); o.y = f2bfr(v[1]); o.z = f2bfr(v[2]); o.w = f2bfr(v[3]);
  *(ushort4*)((unsigned short*)out + (size_t)row * D_ + tid * 4) = o;
}

__global__ __launch_bounds__(256) void ln_kernel_f32(
    const bf16* __restrict__ x, const bf16* __restrict__ g,
    const bf16* __restrict__ b, float* __restrict__ out) {
  const int row = blockIdx.x, tid = threadIdx.x;
  float v[4];
  ln_row(x, g, b, row, tid, v);
  float4 o = {v[0], v[1], v[2], v[3]};
  *(float4*)(out + (size_t)row * D_ + tid * 4) = o;
}

// ---------------------------------------------------------------------------
// Workspace (70.4 MB peak):
//   0- 8 : Xc -> W1c
//   8-16 : Qb -> z1 -> z2
//   16-24: Kbf -> y
//   24-32: Vb -> W2c
//   32-40: Vt;  40-48: ctx;  32-64: hh (over Vt/ctx/fresh)
//   64-70: Wqkv;  70-: vectors [ln1g|ln1b|ln2g|ln2b|b1|b2]
// ---------------------------------------------------------------------------
extern "C" void kernel_launch(void* const* d_in, const int* in_sizes, int n_in,
                              void* d_out, int out_size, void* d_ws, size_t ws_size,
                              hipStream_t stream) {
  (void)in_sizes; (void)n_in; (void)out_size; (void)ws_size;
  const unsigned* Xs = (const unsigned*)d_in[0];

  char* ws = (char*)d_ws;
  const size_t MB = 1024 * 1024;
  bf16* Xc   = (bf16*)(ws + 0 * MB);
  bf16* W1c  = (bf16*)(ws + 0 * MB);
  bf16* Qb   = (bf16*)(ws + 8 * MB);
  bf16* z1   = (bf16*)(ws + 8 * MB);
  bf16* z2   = (bf16*)(ws + 8 * MB);
  bf16* Kbf  = (bf16*)(ws + 16 * MB);
  bf16* y    = (bf16*)(ws + 16 * MB);
  bf16* Vb   = (bf16*)(ws + 24 * MB);
  bf16* W2c  = (bf16*)(ws + 24 * MB);
  bf16* Vt   = (bf16*)(ws + 32 * MB);
  bf16* hh   = (bf16*)(ws + 32 * MB);
  bf16* ctx  = (bf16*)(ws + 40 * MB);
  bf16* Wqkv = (bf16*)(ws + 64 * MB);
  bf16* vecs = (bf16*)(ws + 70 * MB);
  bf16* ln1g = vecs + 0;
  bf16* ln1b = vecs + 1024;
  bf16* ln2g = vecs + 2048;
  bf16* ln2b = vecs + 3072;
  bf16* b1c  = vecs + 4096;
  bf16* b2c  = vecs + 8192;
  bf16* Woc  = Wqkv + (size_t)2048 * D_;

  dim3 blk(256);
  // Phase 0: conversions.
  convert_kernel<<<dim3(MTOK * D_ / 1024), blk, 0, stream>>>(d_in[0], Xs, Xc, MTOK * D_);
  convert3_kernel<<<dim3(3072), blk, 0, stream>>>(d_in[1], d_in[2], d_in[3], Xs, Wqkv);
  convertvec_kernel<<<dim3(9), blk, 0, stream>>>(d_in[4], d_in[5], d_in[6], d_in[7],
                                                 d_in[9], d_in[11], Xs, vecs);

  // Phase 1: fused QKV + V transpose + attention + out-proj + LN1.
  gemm_bt<<<dim3(24, 32), blk, 0, stream>>>(Xc, Wqkv, Qb, nullptr, Kbf, Vb,
                                            MTOK, 3072, D_, 5);
  tpose_v<<<dim3(S_ / 64, B_ * H_), blk, 0, stream>>>(Vb, Vt);
  attn_kernel<<<dim3(S_ / 64, B_ * H_), blk, 0, stream>>>(Qb, Kbf, Vt, ctx);
  gemm64<<<dim3(16, 32), blk, 0, stream>>>(ctx, Woc, z1, nullptr, Xc, MTOK, D_, D_, 2);
  ln_kernel_bf16<<<dim3(MTOK), blk, 0, stream>>>(z1, ln1g, ln1b, y);

  // Phase 2: FFN weights into freed slots, FFN, final LN -> f32 out.
  convert_kernel<<<dim3(FF_ * D_ / 1024), blk, 0, stream>>>(d_in[8], Xs, W1c, FF_ * D_);
  convert_kernel<<<dim3(D_ * FF_ / 1024), blk, 0, stream>>>(d_in[10], Xs, W2c, D_ * FF_);
  gemm_bt<<<dim3(32, 32), blk, 0, stream>>>(y, W1c, hh, b1c, nullptr, nullptr,
                                            MTOK, FF_, D_, 3);
  gemm64<<<dim3(16, 32), blk, 0, stream>>>(hh, W2c, z2, b2c, y, MTOK, D_, FF_, 4);
  ln_kernel_f32<<<dim3(MTOK), blk, 0, stream>>>(z2, ln2g, ln2b, (float*)d_out);
}

// Round 10
// 449.983 us; speedup vs baseline: 5.6062x; 1.0533x over previous
//
#include <hip/hip_runtime.h>
#include <hip/hip_bf16.h>

#define B_ 2
#define S_ 2048
#define D_ 1024
#define H_ 16
#define DH_ 64
#define FF_ 4096
#define MTOK 4096  // B_*S_

using bf16 = __hip_bfloat16;
typedef short s16x8 __attribute__((ext_vector_type(8)));
typedef float f32x4 __attribute__((ext_vector_type(4)));

#define MFMA_BF16(A, Bv, C) __builtin_amdgcn_mfma_f32_16x16x32_bf16(A, Bv, C, 0, 0, 0)

__device__ __forceinline__ void load_lds16(const void* g, void* l) {
  __builtin_amdgcn_global_load_lds(
      (const __attribute__((address_space(1))) void*)g,
      (__attribute__((address_space(3))) void*)l, 16, 0, 0);
}

__device__ __forceinline__ float bfr2f(unsigned short u) {
  return __uint_as_float(((unsigned)u) << 16);
}
__device__ __forceinline__ unsigned short f2bfr(float f) {
  __hip_bfloat16 h = __float2bfloat16(f);
  return *(unsigned short*)&h;
}

// ---------------------------------------------------------------------------
// Inputs are float32 (established r5->r6); sniffer kept as insurance.
// ---------------------------------------------------------------------------
__device__ int sniff_is_bf16(const unsigned* Xw) {
  int cnt = 0;
  for (int i = 0; i < 64; i++) {
    unsigned w = Xw[i];
    unsigned short h0 = (unsigned short)(w & 0xFFFF);
    unsigned short h1 = (unsigned short)(w >> 16);
    int e0 = (h0 >> 7) & 0xFF, e1 = (h1 >> 7) & 0xFF;
    if ((e0 >= 100 && e0 <= 140) || (h0 & 0x7FFF) == 0) cnt++;
    if ((e1 >= 100 && e1 <= 140) || (h1 & 0x7FFF) == 0) cnt++;
  }
  return cnt >= 110;
}

__device__ __forceinline__ void conv4(const void* src, bf16* dst, int i, int isbf) {
  ushort4 o;
  if (isbf) {
    o = *(const ushort4*)((const unsigned short*)src + i);
  } else {
    const float4 f = *(const float4*)((const float*)src + i);
    o.x = f2bfr(f.x); o.y = f2bfr(f.y); o.z = f2bfr(f.z); o.w = f2bfr(f.w);
  }
  *(ushort4*)((unsigned short*)dst + i) = o;
}

__global__ __launch_bounds__(256) void convert_kernel(
    const void* __restrict__ src, const unsigned* __restrict__ Xs,
    bf16* __restrict__ dst, int n) {
  __shared__ int isbf;
  if (threadIdx.x == 0) isbf = sniff_is_bf16(Xs);
  __syncthreads();
  int i = (blockIdx.x * 256 + threadIdx.x) * 4;
  if (i >= n) return;
  conv4(src, dst, i, isbf);
}

// three 1M-element weight tensors -> contiguous Wqkv
__global__ __launch_bounds__(256) void convert3_kernel(
    const void* __restrict__ s0, const void* __restrict__ s1,
    const void* __restrict__ s2, const unsigned* __restrict__ Xs,
    bf16* __restrict__ dst) {
  __shared__ int isbf;
  if (threadIdx.x == 0) isbf = sniff_is_bf16(Xs);
  __syncthreads();
  int i = (blockIdx.x * 256 + threadIdx.x) * 4;  // < 3*1048576
  int seg = i >> 20, loc = i & 1048575;
  const void* src = seg == 0 ? s0 : (seg == 1 ? s1 : s2);
  ushort4 o;
  if (isbf) {
    o = *(const ushort4*)((const unsigned short*)src + loc);
  } else {
    const float4 f = *(const float4*)((const float*)src + loc);
    o.x = f2bfr(f.x); o.y = f2bfr(f.y); o.z = f2bfr(f.z); o.w = f2bfr(f.w);
  }
  *(ushort4*)((unsigned short*)dst + i) = o;
}

// six small vectors -> contiguous block [ln1g|ln1b|ln2g|ln2b|b1|b2]
__global__ __launch_bounds__(256) void convertvec_kernel(
    const void* __restrict__ v0, const void* __restrict__ v1,
    const void* __restrict__ v2, const void* __restrict__ v3,
    const void* __restrict__ v4, const void* __restrict__ v5,
    const unsigned* __restrict__ Xs, bf16* __restrict__ dst) {
  __shared__ int isbf;
  if (threadIdx.x == 0) isbf = sniff_is_bf16(Xs);
  __syncthreads();
  int i = (blockIdx.x * 256 + threadIdx.x) * 4;  // < 9216
  if (i >= 9216) return;
  const void* src; int loc;
  if (i < 4096)      { int s = i >> 10; src = s == 0 ? v0 : s == 1 ? v1 : s == 2 ? v2 : v3; loc = i & 1023; }
  else if (i < 8192) { src = v4; loc = i - 4096; }
  else               { src = v5; loc = i - 8192; }
  ushort4 o;
  if (isbf) {
    o = *(const ushort4*)((const unsigned short*)src + loc);
  } else {
    const float4 f = *(const float4*)((const float*)src + loc);
    o.x = f2bfr(f.x); o.y = f2bfr(f.y); o.z = f2bfr(f.z); o.w = f2bfr(f.w);
  }
  *(ushort4*)((unsigned short*)dst + i) = o;
}

// ---------------------------------------------------------------------------
// 128x128-tile B^T GEMM.
// modes: 3 = relu(acc + bias)   (FFN1)
//        5 = fused QKV: N=3072; hx=gn>>6: <16 Q, <32 K, else V — all head-major
// ---------------------------------------------------------------------------
__global__ __launch_bounds__(256) void gemm_bt(
    const bf16* __restrict__ A, const bf16* __restrict__ Bw,
    bf16* __restrict__ out, const bf16* __restrict__ bias,
    bf16* __restrict__ aux1, bf16* __restrict__ aux2,
    int M, int N, int K, int mode) {
  __shared__ alignas(16) bf16 As[128 * 32];
  __shared__ alignas(16) bf16 Bs[128 * 32];
  const int tid = threadIdx.x;
  const int wave = tid >> 6, lane = tid & 63;
  const int col = lane & 15, quad = lane >> 4;
  const int m0 = blockIdx.y * 128, n0 = blockIdx.x * 128;
  const int wm = (wave >> 1) * 64, wn = (wave & 1) * 64;

  const int srow = wave * 32 + (lane >> 2);
  const int skoff = (lane & 3) * 8;
  const bf16* ag = A + (size_t)(m0 + srow) * K + skoff;
  const bf16* bg = Bw + (size_t)(n0 + srow) * K + skoff;
  bf16* asl = As + wave * 1024;
  bf16* bsl = Bs + wave * 1024;

  const f32x4 fz = {0.f, 0.f, 0.f, 0.f};
  f32x4 acc[4][4];
  for (int i = 0; i < 4; i++)
    for (int j = 0; j < 4; j++) acc[i][j] = fz;

  for (int k0 = 0; k0 < K; k0 += 32) {
    load_lds16(ag + k0, asl);
    load_lds16(ag + k0 + (size_t)16 * K, asl + 512);
    load_lds16(bg + k0, bsl);
    load_lds16(bg + k0 + (size_t)16 * K, bsl + 512);
    __syncthreads();
    s16x8 Af[4], Bf[4];
    for (int t = 0; t < 4; t++) {
      Af[t] = *(const s16x8*)(As + (wm + t * 16 + col) * 32 + quad * 8);
      Bf[t] = *(const s16x8*)(Bs + (wn + t * 16 + col) * 32 + quad * 8);
    }
    for (int mt = 0; mt < 4; mt++)
      for (int nt = 0; nt < 4; nt++)
        acc[mt][nt] = MFMA_BF16(Af[mt], Bf[nt], acc[mt][nt]);
    __syncthreads();
  }

  for (int mt = 0; mt < 4; mt++) {
    for (int nt = 0; nt < 4; nt++) {
      for (int r = 0; r < 4; r++) {
        int gm = m0 + wm + mt * 16 + quad * 4 + r;
        int gn = n0 + wn + nt * 16 + col;
        float v = acc[mt][nt][r];
        if (mode == 5) {
          int b = gm >> 11, s = gm & 2047, hx = gn >> 6, dh = gn & 63;
          bf16* dst = hx < 16 ? out : (hx < 32 ? aux1 : aux2);
          int h = hx & 15;
          dst[(((size_t)(b * H_ + h) * S_ + s) << 6) + dh] = __float2bfloat16(v);
        } else {  // mode 3
          size_t idx = (size_t)gm * N + gn;
          v += __bfloat162float(bias[gn]);
          out[idx] = __float2bfloat16(fmaxf(v, 0.f));
        }
      }
    }
  }
}

// ---------------------------------------------------------------------------
// 128x64-tile B^T GEMM, BK=64 (two 32-wide LDS slabs per barrier -> 6 loads
// in flight, half the barrier drains) + XCD swizzle for grid (16,32):
// per-XCD resident set covers 8m x 8n instead of 32m x 2n.
// modes: 2 = acc + res (out-proj);  4 = acc + bias + res (FFN2)
// ---------------------------------------------------------------------------
__global__ __launch_bounds__(256) void gemm64(
    const bf16* __restrict__ A, const bf16* __restrict__ Bw,
    bf16* __restrict__ out, const bf16* __restrict__ bias,
    const bf16* __restrict__ res, int M, int N, int K, int mode) {
  __shared__ alignas(16) bf16 As[2 * 128 * 32];  // slab0 | slab1
  __shared__ alignas(16) bf16 Bs[2 * 64 * 32];
  const int tid = threadIdx.x;
  const int wave = tid >> 6, lane = tid & 63;
  const int col = lane & 15, quad = lane >> 4;

  // XCD swizzle (grid must be (16,32)): id%8 ~ XCD; give each XCD 8m x 8n.
  const int id = blockIdx.y * 16 + blockIdx.x;
  const int xg = id & 7, kk = id >> 3;
  const int m0 = ((xg >> 1) * 8 + (kk >> 3)) * 128;
  const int n0 = ((xg & 1) * 8 + (kk & 7)) * 64;
  const int wm = (wave >> 1) * 64, wn = (wave & 1) * 32;

  const int srowA = wave * 32 + (lane >> 2);
  const int srowB = wave * 16 + (lane >> 2);
  const int skoff = (lane & 3) * 8;
  const bf16* ag = A + (size_t)(m0 + srowA) * K + skoff;
  const bf16* bg = Bw + (size_t)(n0 + srowB) * K + skoff;
  bf16* asl = As + wave * 1024;
  bf16* bsl = Bs + wave * 512;

  const f32x4 fz = {0.f, 0.f, 0.f, 0.f};
  f32x4 acc[4][2];
  for (int i = 0; i < 4; i++)
    for (int j = 0; j < 2; j++) acc[i][j] = fz;

  for (int k0 = 0; k0 < K; k0 += 64) {
    // slab 0 (k0..k0+31)
    load_lds16(ag + k0, asl);
    load_lds16(ag + k0 + (size_t)16 * K, asl + 512);
    load_lds16(bg + k0, bsl);
    // slab 1 (k0+32..k0+63)
    load_lds16(ag + k0 + 32, asl + 4096);
    load_lds16(ag + k0 + 32 + (size_t)16 * K, asl + 4096 + 512);
    load_lds16(bg + k0 + 32, bsl + 2048);
    __syncthreads();
    for (int s = 0; s < 2; s++) {
      const bf16* Ab = As + s * 4096;
      const bf16* Bb = Bs + s * 2048;
      s16x8 Af[4], Bf[2];
      for (int t = 0; t < 4; t++)
        Af[t] = *(const s16x8*)(Ab + (wm + t * 16 + col) * 32 + quad * 8);
      for (int t = 0; t < 2; t++)
        Bf[t] = *(const s16x8*)(Bb + (wn + t * 16 + col) * 32 + quad * 8);
      for (int mt = 0; mt < 4; mt++)
        for (int nt = 0; nt < 2; nt++)
          acc[mt][nt] = MFMA_BF16(Af[mt], Bf[nt], acc[mt][nt]);
    }
    __syncthreads();
  }

  for (int mt = 0; mt < 4; mt++) {
    for (int nt = 0; nt < 2; nt++) {
      for (int r = 0; r < 4; r++) {
        int gm = m0 + wm + mt * 16 + quad * 4 + r;
        int gn = n0 + wn + nt * 16 + col;
        float v = acc[mt][nt][r];
        size_t idx = (size_t)gm * N + gn;
        if (mode == 2) {
          v += __bfloat162float(res[idx]);
        } else {  // mode 4
          v += __bfloat162float(bias[gn]) + __bfloat162float(res[idx]);
        }
        out[idx] = __float2bfloat16(v);
      }
    }
  }
}

// ---------------------------------------------------------------------------
// V head-major -> Vt [B,H,DH,S] transpose, 64x64 LDS tiles, coalesced I/O.
// ---------------------------------------------------------------------------
__global__ __launch_bounds__(256) void tpose_v(
    const bf16* __restrict__ Vb, bf16* __restrict__ Vt) {
  __shared__ unsigned short Ts[64][72];
  const int tid = threadIdx.x;
  const int bh = blockIdx.y, kt = blockIdx.x;
  const unsigned short* in =
      (const unsigned short*)Vb + (((size_t)bh * S_ + kt * 64) << 6);
  unsigned short* outp =
      (unsigned short*)Vt + ((size_t)bh << 17) + kt * 64;

  const int r = tid >> 2, cc = (tid & 3) * 16;
  s16x8 a = *(const s16x8*)(in + r * 64 + cc);
  s16x8 b = *(const s16x8*)(in + r * 64 + cc + 8);
  for (int j = 0; j < 8; j++) Ts[cc + j][r] = (unsigned short)a[j];
  for (int j = 0; j < 8; j++) Ts[cc + 8 + j][r] = (unsigned short)b[j];
  __syncthreads();
  const int dh = tid >> 2, sc = (tid & 3) * 16;
  s16x8 o0, o1;
  for (int j = 0; j < 8; j++) o0[j] = (short)Ts[dh][sc + j];
  for (int j = 0; j < 8; j++) o1[j] = (short)Ts[dh][sc + 8 + j];
  *(s16x8*)(outp + (size_t)dh * S_ + sc) = o0;
  *(s16x8*)(outp + (size_t)dh * S_ + sc + 8) = o1;
}

// ---------------------------------------------------------------------------
// Tiled flash attention: 256 threads (4 waves), 64 q-rows per block.
// ---------------------------------------------------------------------------
__global__ __launch_bounds__(256) void attn_kernel(
    const bf16* __restrict__ Q, const bf16* __restrict__ Kb,
    const bf16* __restrict__ Vt, bf16* __restrict__ ctx) {
  __shared__ alignas(16) unsigned short Ks[64 * 72];
  __shared__ alignas(16) unsigned short Vs[64 * 72];
  __shared__ alignas(16) unsigned short Ps[4][16 * 72];
  const int tid = threadIdx.x;
  const int wave = tid >> 6, lane = tid & 63;
  const int col = lane & 15, quad = lane >> 4;
  const int bh = blockIdx.y;
  const int q0 = blockIdx.x * 64 + wave * 16;
  const bf16* Qp = Q + (size_t)bh * S_ * DH_;
  const bf16* Kp = Kb + (size_t)bh * S_ * DH_;
  const bf16* Vp = Vt + (size_t)bh * DH_ * S_;
  unsigned short* Pw = Ps[wave];

  s16x8 qf0 = *(const s16x8*)(Qp + (size_t)(q0 + col) * DH_ + quad * 8);
  s16x8 qf1 = *(const s16x8*)(Qp + (size_t)(q0 + col) * DH_ + 32 + quad * 8);

  const f32x4 fz = {0.f, 0.f, 0.f, 0.f};
  f32x4 accv[4];
  for (int t = 0; t < 4; t++) accv[t] = fz;
  float lpart[4] = {0.f, 0.f, 0.f, 0.f};

  const int srow = tid >> 2, sseg = (tid & 3) * 16;

  for (int kt = 0; kt < S_; kt += 64) {
    s16x8 k0 = *(const s16x8*)(Kp + (size_t)(kt + srow) * DH_ + sseg);
    s16x8 k1 = *(const s16x8*)(Kp + (size_t)(kt + srow) * DH_ + sseg + 8);
    s16x8 v0 = *(const s16x8*)(Vp + (size_t)srow * S_ + kt + sseg);
    s16x8 v1 = *(const s16x8*)(Vp + (size_t)srow * S_ + kt + sseg + 8);
    __syncthreads();
    *(s16x8*)(Ks + srow * 72 + sseg) = k0;
    *(s16x8*)(Ks + srow * 72 + sseg + 8) = k1;
    *(s16x8*)(Vs + srow * 72 + sseg) = v0;
    *(s16x8*)(Vs + srow * 72 + sseg + 8) = v1;
    __syncthreads();

    for (int t = 0; t < 4; t++) {
      s16x8 kf0 = *(const s16x8*)(Ks + (t * 16 + col) * 72 + quad * 8);
      s16x8 kf1 = *(const s16x8*)(Ks + (t * 16 + col) * 72 + 32 + quad * 8);
      f32x4 s = fz;
      s = MFMA_BF16(qf0, kf0, s);
      s = MFMA_BF16(qf1, kf1, s);
      for (int r = 0; r < 4; r++) {
        float e = __expf(fmaxf(s[r] * 0.125f, 0.f));
        lpart[r] += e;
        Pw[(quad * 4 + r) * 72 + t * 16 + col] = f2bfr(e);
      }
    }
    s16x8 pf0 = *(const s16x8*)(Pw + col * 72 + quad * 8);
    s16x8 pf1 = *(const s16x8*)(Pw + col * 72 + 32 + quad * 8);
    for (int t = 0; t < 4; t++) {
      s16x8 vf0 = *(const s16x8*)(Vs + (t * 16 + col) * 72 + quad * 8);
      s16x8 vf1 = *(const s16x8*)(Vs + (t * 16 + col) * 72 + 32 + quad * 8);
      accv[t] = MFMA_BF16(pf0, vf0, accv[t]);
      accv[t] = MFMA_BF16(pf1, vf1, accv[t]);
    }
  }

  for (int off = 1; off < 16; off <<= 1)
    for (int r = 0; r < 4; r++) lpart[r] += __shfl_xor(lpart[r], off, 64);
  const int b = bh >> 4, h = bh & 15;
  for (int r = 0; r < 4; r++) {
    float rl = 1.f / lpart[r];
    size_t base = (size_t)(b * S_ + q0 + quad * 4 + r) * D_ + h * DH_;
    for (int t = 0; t < 4; t++)
      ctx[base + t * 16 + col] = __float2bfloat16(accv[t][r] * rl);
  }
}

// ---------------------------------------------------------------------------
// LayerNorm over last dim (1024); bf16 out (mid) or f32 out (final).
// ---------------------------------------------------------------------------
__device__ __forceinline__ void ln_row(
    const bf16* __restrict__ x, const bf16* __restrict__ g,
    const bf16* __restrict__ b, int row, int tid, float vout[4]) {
  const int lane = tid & 63, wave = tid >> 6;
  const unsigned short* xr = (const unsigned short*)x + (size_t)row * D_;
  ushort4 xv = *(const ushort4*)(xr + tid * 4);
  float v[4];
  v[0] = bfr2f(xv.x); v[1] = bfr2f(xv.y); v[2] = bfr2f(xv.z); v[3] = bfr2f(xv.w);
  float sum = v[0] + v[1] + v[2] + v[3];
  float sq = v[0] * v[0] + v[1] * v[1] + v[2] * v[2] + v[3] * v[3];
  for (int off = 32; off > 0; off >>= 1) {
    sum += __shfl_xor(sum, off, 64);
    sq += __shfl_xor(sq, off, 64);
  }
  __shared__ float red[4][2];
  if (lane == 0) { red[wave][0] = sum; red[wave][1] = sq; }
  __syncthreads();
  sum = red[0][0] + red[1][0] + red[2][0] + red[3][0];
  sq = red[0][1] + red[1][1] + red[2][1] + red[3][1];
  float mu = sum * (1.f / D_);
  float var = sq * (1.f / D_) - mu * mu;
  float rs = rsqrtf(var + 1e-5f);
  ushort4 gv = *(const ushort4*)((const unsigned short*)g + tid * 4);
  ushort4 bv = *(const ushort4*)((const unsigned short*)b + tid * 4);
  vout[0] = (v[0] - mu) * rs * bfr2f(gv.x) + bfr2f(bv.x);
  vout[1] = (v[1] - mu) * rs * bfr2f(gv.y) + bfr2f(bv.y);
  vout[2] = (v[2] - mu) * rs * bfr2f(gv.z) + bfr2f(bv.z);
  vout[3] = (v[3] - mu) * rs * bfr2f(gv.w) + bfr2f(bv.w);
}

__global__ __launch_bounds__(256) void ln_kernel_bf16(
    const bf16* __restrict__ x, const bf16* __restrict__ g,
    const bf16* __restrict__ b, bf16* __restrict__ out) {
  const int row = blockIdx.x, tid = threadIdx.x;
  float v[4];
  ln_row(x, g, b, row, tid, v);
  ushort4 o;
  o.x = f2bfr(v[0]); o.y = f2bfr(v[1]); o.z = f2bfr(v[2]); o.w = f2bfr(v[3]);
  *(ushort4*)((unsigned short*)out + (size_t)row * D_ + tid * 4) = o;
}

__global__ __launch_bounds__(256) void ln_kernel_f32(
    const bf16* __restrict__ x, const bf16* __restrict__ g,
    const bf16* __restrict__ b, float* __restrict__ out) {
  const int row = blockIdx.x, tid = threadIdx.x;
  float v[4];
  ln_row(x, g, b, row, tid, v);
  float4 o = {v[0], v[1], v[2], v[3]};
  *(float4*)(out + (size_t)row * D_ + tid * 4) = o;
}

// ---------------------------------------------------------------------------
// Workspace (70.4 MB peak):
//   0- 8 : Xc -> W1c
//   8-16 : Qb -> z1 -> z2
//   16-24: Kbf -> y
//   24-32: Vb -> W2c
//   32-40: Vt;  40-48: ctx;  32-64: hh (over Vt/ctx/fresh)
//   64-70: Wqkv;  70-: vectors [ln1g|ln1b|ln2g|ln2b|b1|b2]
// ---------------------------------------------------------------------------
extern "C" void kernel_launch(void* const* d_in, const int* in_sizes, int n_in,
                              void* d_out, int out_size, void* d_ws, size_t ws_size,
                              hipStream_t stream) {
  (void)in_sizes; (void)n_in; (void)out_size; (void)ws_size;
  const unsigned* Xs = (const unsigned*)d_in[0];

  char* ws = (char*)d_ws;
  const size_t MB = 1024 * 1024;
  bf16* Xc   = (bf16*)(ws + 0 * MB);
  bf16* W1c  = (bf16*)(ws + 0 * MB);
  bf16* Qb   = (bf16*)(ws + 8 * MB);
  bf16* z1   = (bf16*)(ws + 8 * MB);
  bf16* z2   = (bf16*)(ws + 8 * MB);
  bf16* Kbf  = (bf16*)(ws + 16 * MB);
  bf16* y    = (bf16*)(ws + 16 * MB);
  bf16* Vb   = (bf16*)(ws + 24 * MB);
  bf16* W2c  = (bf16*)(ws + 24 * MB);
  bf16* Vt   = (bf16*)(ws + 32 * MB);
  bf16* hh   = (bf16*)(ws + 32 * MB);
  bf16* ctx  = (bf16*)(ws + 40 * MB);
  bf16* Wqkv = (bf16*)(ws + 64 * MB);
  bf16* vecs = (bf16*)(ws + 70 * MB);
  bf16* ln1g = vecs + 0;
  bf16* ln1b = vecs + 1024;
  bf16* ln2g = vecs + 2048;
  bf16* ln2b = vecs + 3072;
  bf16* b1c  = vecs + 4096;
  bf16* b2c  = vecs + 8192;
  bf16* Woc  = Wqkv + (size_t)2048 * D_;

  dim3 blk(256);
  // Phase 0: conversions.
  convert_kernel<<<dim3(MTOK * D_ / 1024), blk, 0, stream>>>(d_in[0], Xs, Xc, MTOK * D_);
  convert3_kernel<<<dim3(3072), blk, 0, stream>>>(d_in[1], d_in[2], d_in[3], Xs, Wqkv);
  convertvec_kernel<<<dim3(9), blk, 0, stream>>>(d_in[4], d_in[5], d_in[6], d_in[7],
                                                 d_in[9], d_in[11], Xs, vecs);

  // Phase 1: fused QKV + V transpose + attention + out-proj + LN1.
  gemm_bt<<<dim3(24, 32), blk, 0, stream>>>(Xc, Wqkv, Qb, nullptr, Kbf, Vb,
                                            MTOK, 3072, D_, 5);
  tpose_v<<<dim3(S_ / 64, B_ * H_), blk, 0, stream>>>(Vb, Vt);
  attn_kernel<<<dim3(S_ / 64, B_ * H_), blk, 0, stream>>>(Qb, Kbf, Vt, ctx);
  gemm64<<<dim3(16, 32), blk, 0, stream>>>(ctx, Woc, z1, nullptr, Xc, MTOK, D_, D_, 2);
  ln_kernel_bf16<<<dim3(MTOK), blk, 0, stream>>>(z1, ln1g, ln1b, y);

  // Phase 2: FFN weights into freed slots, FFN, final LN -> f32 out.
  convert_kernel<<<dim3(FF_ * D_ / 1024), blk, 0, stream>>>(d_in[8], Xs, W1c, FF_ * D_);
  convert_kernel<<<dim3(D_ * FF_ / 1024), blk, 0, stream>>>(d_in[10], Xs, W2c, D_ * FF_);
  gemm_bt<<<dim3(32, 32), blk, 0, stream>>>(y, W1c, hh, b1c, nullptr, nullptr,
                                            MTOK, FF_, D_, 3);
  gemm64<<<dim3(16, 32), blk, 0, stream>>>(hh, W2c, z2, b2c, y, MTOK, D_, FF_, 4);
  ln_kernel_f32<<<dim3(MTOK), blk, 0, stream>>>(z2, ln2g, ln2b, (float*)d_out);
}